// Round 1
// baseline (1532.103 us; speedup 1.0000x reference)
//
#include <hip/hip_runtime.h>
#include <math.h>

#define N_NODES 100000
#define FIN     512
#define H1H     8
#define C1C     8
#define HC1     64
#define NCLS    40
#define NEG_SLOPE 0.2f

// ---------------- Layer-1 GEMM: h1[N,64] = x[N,512] @ W1[512,64] ----------------
// Block = 256 threads = 64 cols x 4 row-groups; each row-group covers 16 rows.
// x loads are wave-uniform (broadcast), W1 loads are fully coalesced (256B/wave).
__global__ __launch_bounds__(256) void k_gemm1(const float* __restrict__ x,
                                               const float* __restrict__ W1,
                                               float* __restrict__ h1) {
    const int col  = threadIdx.x & 63;
    const int rg   = threadIdx.x >> 6;
    const int row0 = blockIdx.x * 64 + rg * 16;
    if (row0 >= N_NODES) return;   // N divisible by 16 -> row-groups are all-or-nothing

    float acc[16];
#pragma unroll
    for (int i = 0; i < 16; i++) acc[i] = 0.f;

    for (int k = 0; k < FIN; k += 4) {
        const float w0 = W1[(k + 0) * HC1 + col];
        const float w1 = W1[(k + 1) * HC1 + col];
        const float w2 = W1[(k + 2) * HC1 + col];
        const float w3 = W1[(k + 3) * HC1 + col];
#pragma unroll
        for (int i = 0; i < 16; i++) {
            const float4 xv = *(const float4*)(x + (size_t)(row0 + i) * FIN + k);
            acc[i] = fmaf(xv.x, w0, fmaf(xv.y, w1, fmaf(xv.z, w2, fmaf(xv.w, w3, acc[i]))));
        }
    }
#pragma unroll
    for (int i = 0; i < 16; i++)
        h1[(size_t)(row0 + i) * HC1 + col] = acc[i];
}

// ---------------- Layer-1 attention dots: a_src[n,h], a_dst[n,h] ----------------
__global__ __launch_bounds__(256) void k_att1(const float* __restrict__ h1,
                                              const float* __restrict__ att_src,
                                              const float* __restrict__ att_dst,
                                              float* __restrict__ a_src,
                                              float* __restrict__ a_dst) {
    const int tid = blockIdx.x * 256 + threadIdx.x;
    if (tid >= N_NODES * H1H) return;
    const int n = tid >> 3, hh = tid & 7;
    const float* hp = h1 + (size_t)n * HC1 + hh * C1C;
    float s = 0.f, d = 0.f;
#pragma unroll
    for (int c = 0; c < C1C; c++) {
        const float v = hp[c];
        s = fmaf(v, att_src[hh * C1C + c], s);
        d = fmaf(v, att_dst[hh * C1C + c], d);
    }
    a_src[tid] = s;
    a_dst[tid] = d;
}

// ---------------- CSR build: histogram -> scan -> scatter ----------------
__global__ void k_hist(const int* __restrict__ dst, int E, int* __restrict__ deg) {
    const int e = blockIdx.x * 256 + threadIdx.x;
    if (e < E) atomicAdd(&deg[dst[e]], 1);
}

__global__ __launch_bounds__(256) void k_scan1(const int* __restrict__ deg,
                                               int* __restrict__ offs,
                                               int* __restrict__ bsum) {
    __shared__ int sm[256];
    const int i = blockIdx.x * 256 + threadIdx.x;
    const int v = (i < N_NODES) ? deg[i] : 0;
    sm[threadIdx.x] = v;
    __syncthreads();
    for (int off = 1; off < 256; off <<= 1) {
        const int t = (threadIdx.x >= off) ? sm[threadIdx.x - off] : 0;
        __syncthreads();
        sm[threadIdx.x] += t;
        __syncthreads();
    }
    if (i < N_NODES) offs[i] = sm[threadIdx.x] - v;           // exclusive
    if (threadIdx.x == 255) bsum[blockIdx.x] = sm[255];
}

__global__ __launch_bounds__(512) void k_scan2(const int* __restrict__ bsum,
                                               int* __restrict__ boff, int nb) {
    __shared__ int sm[512];
    const int v = (threadIdx.x < nb) ? bsum[threadIdx.x] : 0;
    sm[threadIdx.x] = v;
    __syncthreads();
    for (int off = 1; off < 512; off <<= 1) {
        const int t = (threadIdx.x >= off) ? sm[threadIdx.x - off] : 0;
        __syncthreads();
        sm[threadIdx.x] += t;
        __syncthreads();
    }
    if (threadIdx.x < nb) boff[threadIdx.x] = sm[threadIdx.x] - v;  // exclusive
}

__global__ __launch_bounds__(256) void k_scan3(int* __restrict__ offs,
                                               const int* __restrict__ boff,
                                               int* __restrict__ cursor, int E) {
    const int i = blockIdx.x * 256 + threadIdx.x;
    if (i < N_NODES) {
        const int o = offs[i] + boff[blockIdx.x];
        offs[i] = o;
        cursor[i] = o;
    }
    if (i == 0) offs[N_NODES] = E;
}

__global__ void k_scatter(const int* __restrict__ src, const int* __restrict__ dst,
                          int E, int* __restrict__ cursor, int* __restrict__ srcsort) {
    const int e = blockIdx.x * 256 + threadIdx.x;
    if (e < E) {
        const int pos = atomicAdd(&cursor[dst[e]], 1);
        srcsort[pos] = src[e];
    }
}

// ---------------- Layer-1 softmax + aggregate + bias + ELU ----------------
// One wave per destination node; lane = output channel (h = lane/8).
__global__ __launch_bounds__(256) void k_agg1(const float* __restrict__ h1,
                                              const float* __restrict__ a_src,
                                              const float* __restrict__ a_dst,
                                              const int* __restrict__ offs,
                                              const int* __restrict__ srcsort,
                                              const float* __restrict__ b1,
                                              float* __restrict__ h1e) {
    const int n = blockIdx.x * 4 + (threadIdx.x >> 6);
    if (n >= N_NODES) return;
    const int lane = threadIdx.x & 63;
    const int hh   = lane >> 3;
    const float adn = a_dst[n * H1H + hh];
    const int beg = offs[n], end = offs[n + 1];

    float e0 = a_src[n * H1H + hh] + adn;
    e0 = e0 > 0.f ? e0 : NEG_SLOPE * e0;
    float m = e0;
    for (int j = beg; j < end; j++) {
        const int s = srcsort[j];
        float e = a_src[s * H1H + hh] + adn;
        e = e > 0.f ? e : NEG_SLOPE * e;
        m = fmaxf(m, e);
    }
    const float w0 = __expf(e0 - m);
    float denom = w0;
    float acc = w0 * h1[(size_t)n * HC1 + lane];
    for (int j = beg; j < end; j++) {
        const int s = srcsort[j];
        float e = a_src[s * H1H + hh] + adn;
        e = e > 0.f ? e : NEG_SLOPE * e;
        const float wj = __expf(e - m);
        denom += wj;
        acc = fmaf(wj, h1[(size_t)s * HC1 + lane], acc);
    }
    float v = acc / denom + b1[lane];
    h1e[(size_t)n * HC1 + lane] = v > 0.f ? v : (__expf(v) - 1.f);
}

// ---------------- Layer-2 GEMM (64->40) + attention dots ----------------
// One wave per node: lane loads one of 64 h values; broadcast via shfl.
__global__ __launch_bounds__(256) void k_gemm2(const float* __restrict__ h1e,
                                               const float* __restrict__ W2,
                                               const float* __restrict__ att_src2,
                                               const float* __restrict__ att_dst2,
                                               float* __restrict__ h2,
                                               float* __restrict__ a_src2,
                                               float* __restrict__ a_dst2) {
    const int n = blockIdx.x * 4 + (threadIdx.x >> 6);
    if (n >= N_NODES) return;
    const int lane = threadIdx.x & 63;
    const float xv = h1e[(size_t)n * HC1 + lane];
    float acc = 0.f;
#pragma unroll
    for (int k = 0; k < HC1; k++) {
        const float xk = __shfl(xv, k, 64);
        const float wv = (lane < NCLS) ? W2[k * NCLS + lane] : 0.f;
        acc = fmaf(xk, wv, acc);
    }
    if (lane < NCLS) h2[(size_t)n * NCLS + lane] = acc;
    float ps = (lane < NCLS) ? acc * att_src2[lane] : 0.f;
    float pd = (lane < NCLS) ? acc * att_dst2[lane] : 0.f;
#pragma unroll
    for (int off = 32; off; off >>= 1) {
        ps += __shfl_xor(ps, off, 64);
        pd += __shfl_xor(pd, off, 64);
    }
    if (lane == 0) {
        a_src2[n] = ps;
        a_dst2[n] = pd;
    }
}

// ---------------- Layer-2 softmax-aggregate + bias + class softmax ----------------
__global__ __launch_bounds__(256) void k_agg2(const float* __restrict__ h2,
                                              const float* __restrict__ a_src,
                                              const float* __restrict__ a_dst,
                                              const int* __restrict__ offs,
                                              const int* __restrict__ srcsort,
                                              const float* __restrict__ b2,
                                              float* __restrict__ out) {
    const int n = blockIdx.x * 4 + (threadIdx.x >> 6);
    if (n >= N_NODES) return;
    const int lane = threadIdx.x & 63;
    const float adn = a_dst[n];
    const int beg = offs[n], end = offs[n + 1];

    float e0 = a_src[n] + adn;
    e0 = e0 > 0.f ? e0 : NEG_SLOPE * e0;
    float m = e0;
    for (int j = beg; j < end; j++) {
        const int s = srcsort[j];
        float e = a_src[s] + adn;
        e = e > 0.f ? e : NEG_SLOPE * e;
        m = fmaxf(m, e);
    }
    const float w0 = __expf(e0 - m);
    float denom = w0;
    float acc = (lane < NCLS) ? w0 * h2[(size_t)n * NCLS + lane] : 0.f;
    for (int j = beg; j < end; j++) {
        const int s = srcsort[j];
        float e = a_src[s] + adn;
        e = e > 0.f ? e : NEG_SLOPE * e;
        const float wj = __expf(e - m);
        denom += wj;
        if (lane < NCLS) acc = fmaf(wj, h2[(size_t)s * NCLS + lane], acc);
    }
    float o = (lane < NCLS) ? (acc / denom + b2[lane]) : -INFINITY;
    // softmax over the 40 classes (in-wave)
    float mx = o;
#pragma unroll
    for (int off = 32; off; off >>= 1) mx = fmaxf(mx, __shfl_xor(mx, off, 64));
    const float ex = (lane < NCLS) ? __expf(o - mx) : 0.f;
    float sm = ex;
#pragma unroll
    for (int off = 32; off; off >>= 1) sm += __shfl_xor(sm, off, 64);
    if (lane < NCLS) out[(size_t)n * NCLS + lane] = ex / sm;
}

// ---------------- launcher ----------------
extern "C" void kernel_launch(void* const* d_in, const int* in_sizes, int n_in,
                              void* d_out, int out_size, void* d_ws, size_t ws_size,
                              hipStream_t stream) {
    const float* x   = (const float*)d_in[0];
    const int*   ei  = (const int*)d_in[1];
    const float* W1v = (const float*)d_in[2];
    const float* as1 = (const float*)d_in[3];
    const float* ad1 = (const float*)d_in[4];
    const float* b1  = (const float*)d_in[5];
    const float* W2v = (const float*)d_in[6];
    const float* as2 = (const float*)d_in[7];
    const float* ad2 = (const float*)d_in[8];
    const float* b2  = (const float*)d_in[9];
    const int E = in_sizes[1] / 2;
    const int* esrc = ei;
    const int* edst = ei + E;

    char* wp = (char*)d_ws;
    auto alloc = [&](size_t bytes) {
        char* p = wp;
        wp += (bytes + 255) & ~(size_t)255;
        return p;
    };
    float* h1     = (float*)alloc((size_t)N_NODES * HC1 * 4);
    float* h1e    = (float*)alloc((size_t)N_NODES * HC1 * 4);
    float* a_src1 = (float*)alloc((size_t)N_NODES * H1H * 4);
    float* a_dst1 = (float*)alloc((size_t)N_NODES * H1H * 4);
    float* a_src2 = (float*)alloc((size_t)N_NODES * 4);
    float* a_dst2 = (float*)alloc((size_t)N_NODES * 4);
    int*   deg    = (int*)alloc((size_t)N_NODES * 4);
    int*   offs   = (int*)alloc((size_t)(N_NODES + 1) * 4);
    int*   cursor = (int*)alloc((size_t)N_NODES * 4);
    int*   bsum   = (int*)alloc(512 * 4);
    int*   boff   = (int*)alloc(512 * 4);
    int*   srcsort= (int*)alloc((size_t)E * 4);
    float* h2     = h1;  // h1 is dead after k_agg1; reuse its space for h2

    hipMemsetAsync(deg, 0, (size_t)N_NODES * 4, stream);

    k_gemm1<<<(N_NODES + 63) / 64, 256, 0, stream>>>(x, W1v, h1);
    k_att1<<<(N_NODES * H1H + 255) / 256, 256, 0, stream>>>(h1, as1, ad1, a_src1, a_dst1);
    k_hist<<<(E + 255) / 256, 256, 0, stream>>>(edst, E, deg);
    const int NB = (N_NODES + 255) / 256;
    k_scan1<<<NB, 256, 0, stream>>>(deg, offs, bsum);
    k_scan2<<<1, 512, 0, stream>>>(bsum, boff, NB);
    k_scan3<<<NB, 256, 0, stream>>>(offs, boff, cursor, E);
    k_scatter<<<(E + 255) / 256, 256, 0, stream>>>(esrc, edst, E, cursor, srcsort);
    k_agg1<<<(N_NODES + 3) / 4, 256, 0, stream>>>(h1, a_src1, a_dst1, offs, srcsort, b1, h1e);
    k_gemm2<<<(N_NODES + 3) / 4, 256, 0, stream>>>(h1e, W2v, as2, ad2, h2, a_src2, a_dst2);
    k_agg2<<<(N_NODES + 3) / 4, 256, 0, stream>>>(h2, a_src2, a_dst2, offs, srcsort, b2, (float*)d_out);
}

// Round 2
// 1162.753 us; speedup vs baseline: 1.3177x; 1.3177x over previous
//
#include <hip/hip_runtime.h>
#include <math.h>

#define N_NODES 100000
#define FIN     512
#define H1H     8
#define C1C     8
#define HC1     64
#define NCLS    40
#define NEG_SLOPE 0.2f

// ---------------- Layer-1 GEMM: h1[N,64] = x[N,512] @ W1[512,64] ----------------
// LDS-tiled: 128 rows x 64 cols per 256-thread block, BK=32.
// xs stored transposed [k][row] (ld=132: conflict-free b128 compute reads, 16B aligned);
// each thread computes an 8x4 micro-tile -> 32 fma per k-step vs 3 ds_read_b128.
#define TM 128
#define TN 64
#define BK 32
#define XS_LD 132

__global__ __launch_bounds__(256) void k_gemm1(const float* __restrict__ x,
                                               const float* __restrict__ W1,
                                               float* __restrict__ h1) {
    __shared__ float xs[BK][XS_LD];
    __shared__ float ws[BK][TN];
    const int tx = threadIdx.x;
    const int row_base = blockIdx.x * TM;

    const int cg = (tx & 15) << 2;   // this thread's 4-col base
    const int rg = (tx >> 4) << 3;   // this thread's 8-row base (within tile)

    float acc[8][4];
#pragma unroll
    for (int i = 0; i < 8; i++)
#pragma unroll
        for (int j = 0; j < 4; j++) acc[i][j] = 0.f;

    for (int k0 = 0; k0 < FIN; k0 += BK) {
        // stage x tile: 128 rows x 32 floats = 1024 float4, 4 per thread (coalesced)
#pragma unroll
        for (int i = 0; i < 4; i++) {
            const int f  = tx + 256 * i;
            const int r  = f >> 3;          // 8 float4 per row
            const int kq = (f & 7) << 2;
            const int gr = row_base + r;
            float4 v = make_float4(0.f, 0.f, 0.f, 0.f);
            if (gr < N_NODES) v = *(const float4*)(x + (size_t)gr * FIN + k0 + kq);
            xs[kq + 0][r] = v.x;
            xs[kq + 1][r] = v.y;
            xs[kq + 2][r] = v.z;
            xs[kq + 3][r] = v.w;
        }
        // stage W tile: 32 x 64 = 512 float4, 2 per thread (coalesced)
#pragma unroll
        for (int i = 0; i < 2; i++) {
            const int f  = tx + 256 * i;
            const int kk = f >> 4;          // 16 float4 per W row
            const int c4 = (f & 15) << 2;
            *(float4*)&ws[kk][c4] = *(const float4*)(W1 + (size_t)(k0 + kk) * TN + c4);
        }
        __syncthreads();
#pragma unroll
        for (int k = 0; k < BK; k++) {
            const float4 xa = *(const float4*)&xs[k][rg];
            const float4 xb = *(const float4*)&xs[k][rg + 4];
            const float4 wv = *(const float4*)&ws[k][cg];
            const float xr[8] = {xa.x, xa.y, xa.z, xa.w, xb.x, xb.y, xb.z, xb.w};
#pragma unroll
            for (int i = 0; i < 8; i++) {
                acc[i][0] = fmaf(xr[i], wv.x, acc[i][0]);
                acc[i][1] = fmaf(xr[i], wv.y, acc[i][1]);
                acc[i][2] = fmaf(xr[i], wv.z, acc[i][2]);
                acc[i][3] = fmaf(xr[i], wv.w, acc[i][3]);
            }
        }
        __syncthreads();
    }
#pragma unroll
    for (int i = 0; i < 8; i++) {
        const int gr = row_base + rg + i;
        if (gr < N_NODES)
            *(float4*)(h1 + (size_t)gr * HC1 + cg) =
                make_float4(acc[i][0], acc[i][1], acc[i][2], acc[i][3]);
    }
}

// ---------------- Layer-1 attention dots: a_src[n,h], a_dst[n,h] ----------------
__global__ __launch_bounds__(256) void k_att1(const float* __restrict__ h1,
                                              const float* __restrict__ att_src,
                                              const float* __restrict__ att_dst,
                                              float* __restrict__ a_src,
                                              float* __restrict__ a_dst) {
    const int tid = blockIdx.x * 256 + threadIdx.x;
    if (tid >= N_NODES * H1H) return;
    const int n = tid >> 3, hh = tid & 7;
    const float* hp = h1 + (size_t)n * HC1 + hh * C1C;
    float s = 0.f, d = 0.f;
#pragma unroll
    for (int c = 0; c < C1C; c++) {
        const float v = hp[c];
        s = fmaf(v, att_src[hh * C1C + c], s);
        d = fmaf(v, att_dst[hh * C1C + c], d);
    }
    a_src[tid] = s;
    a_dst[tid] = d;
}

// ---------------- CSR build: histogram -> scan -> scatter ----------------
__global__ void k_hist(const int* __restrict__ dst, int E, int* __restrict__ deg) {
    const int e = blockIdx.x * 256 + threadIdx.x;
    if (e < E) atomicAdd(&deg[dst[e]], 1);
}

__global__ __launch_bounds__(256) void k_scan1(const int* __restrict__ deg,
                                               int* __restrict__ offs,
                                               int* __restrict__ bsum) {
    __shared__ int sm[256];
    const int i = blockIdx.x * 256 + threadIdx.x;
    const int v = (i < N_NODES) ? deg[i] : 0;
    sm[threadIdx.x] = v;
    __syncthreads();
    for (int off = 1; off < 256; off <<= 1) {
        const int t = (threadIdx.x >= off) ? sm[threadIdx.x - off] : 0;
        __syncthreads();
        sm[threadIdx.x] += t;
        __syncthreads();
    }
    if (i < N_NODES) offs[i] = sm[threadIdx.x] - v;           // exclusive
    if (threadIdx.x == 255) bsum[blockIdx.x] = sm[255];
}

__global__ __launch_bounds__(512) void k_scan2(const int* __restrict__ bsum,
                                               int* __restrict__ boff, int nb) {
    __shared__ int sm[512];
    const int v = (threadIdx.x < nb) ? bsum[threadIdx.x] : 0;
    sm[threadIdx.x] = v;
    __syncthreads();
    for (int off = 1; off < 512; off <<= 1) {
        const int t = (threadIdx.x >= off) ? sm[threadIdx.x - off] : 0;
        __syncthreads();
        sm[threadIdx.x] += t;
        __syncthreads();
    }
    if (threadIdx.x < nb) boff[threadIdx.x] = sm[threadIdx.x] - v;  // exclusive
}

__global__ __launch_bounds__(256) void k_scan3(int* __restrict__ offs,
                                               const int* __restrict__ boff,
                                               int* __restrict__ cursor, int E) {
    const int i = blockIdx.x * 256 + threadIdx.x;
    if (i < N_NODES) {
        const int o = offs[i] + boff[blockIdx.x];
        offs[i] = o;
        cursor[i] = o;
    }
    if (i == 0) offs[N_NODES] = E;
}

__global__ void k_scatter(const int* __restrict__ src, const int* __restrict__ dst,
                          int E, int* __restrict__ cursor, int* __restrict__ srcsort) {
    const int e = blockIdx.x * 256 + threadIdx.x;
    if (e < E) {
        const int pos = atomicAdd(&cursor[dst[e]], 1);
        srcsort[pos] = src[e];
    }
}

// ---------------- Layer-1 softmax + aggregate + bias + ELU ----------------
// One wave per destination node; lane = output channel (h = lane/8).
__global__ __launch_bounds__(256) void k_agg1(const float* __restrict__ h1,
                                              const float* __restrict__ a_src,
                                              const float* __restrict__ a_dst,
                                              const int* __restrict__ offs,
                                              const int* __restrict__ srcsort,
                                              const float* __restrict__ b1,
                                              float* __restrict__ h1e) {
    const int n = blockIdx.x * 4 + (threadIdx.x >> 6);
    if (n >= N_NODES) return;
    const int lane = threadIdx.x & 63;
    const int hh   = lane >> 3;
    const float adn = a_dst[n * H1H + hh];
    const int beg = offs[n], end = offs[n + 1];

    float e0 = a_src[n * H1H + hh] + adn;
    e0 = e0 > 0.f ? e0 : NEG_SLOPE * e0;
    float m = e0;
    for (int j = beg; j < end; j++) {
        const int s = srcsort[j];
        float e = a_src[s * H1H + hh] + adn;
        e = e > 0.f ? e : NEG_SLOPE * e;
        m = fmaxf(m, e);
    }
    const float w0 = __expf(e0 - m);
    float denom = w0;
    float acc = w0 * h1[(size_t)n * HC1 + lane];
    for (int j = beg; j < end; j++) {
        const int s = srcsort[j];
        float e = a_src[s * H1H + hh] + adn;
        e = e > 0.f ? e : NEG_SLOPE * e;
        const float wj = __expf(e - m);
        denom += wj;
        acc = fmaf(wj, h1[(size_t)s * HC1 + lane], acc);
    }
    float v = acc / denom + b1[lane];
    h1e[(size_t)n * HC1 + lane] = v > 0.f ? v : (__expf(v) - 1.f);
}

// ---------------- Layer-2 GEMM (64->40) + attention dots ----------------
__global__ __launch_bounds__(256) void k_gemm2(const float* __restrict__ h1e,
                                               const float* __restrict__ W2,
                                               const float* __restrict__ att_src2,
                                               const float* __restrict__ att_dst2,
                                               float* __restrict__ h2,
                                               float* __restrict__ a_src2,
                                               float* __restrict__ a_dst2) {
    const int n = blockIdx.x * 4 + (threadIdx.x >> 6);
    if (n >= N_NODES) return;
    const int lane = threadIdx.x & 63;
    const float xv = h1e[(size_t)n * HC1 + lane];
    float acc = 0.f;
#pragma unroll
    for (int k = 0; k < HC1; k++) {
        const float xk = __shfl(xv, k, 64);
        const float wv = (lane < NCLS) ? W2[k * NCLS + lane] : 0.f;
        acc = fmaf(xk, wv, acc);
    }
    if (lane < NCLS) h2[(size_t)n * NCLS + lane] = acc;
    float ps = (lane < NCLS) ? acc * att_src2[lane] : 0.f;
    float pd = (lane < NCLS) ? acc * att_dst2[lane] : 0.f;
#pragma unroll
    for (int off = 32; off; off >>= 1) {
        ps += __shfl_xor(ps, off, 64);
        pd += __shfl_xor(pd, off, 64);
    }
    if (lane == 0) {
        a_src2[n] = ps;
        a_dst2[n] = pd;
    }
}

// ---------------- Layer-2 softmax-aggregate + bias + class softmax ----------------
__global__ __launch_bounds__(256) void k_agg2(const float* __restrict__ h2,
                                              const float* __restrict__ a_src,
                                              const float* __restrict__ a_dst,
                                              const int* __restrict__ offs,
                                              const int* __restrict__ srcsort,
                                              const float* __restrict__ b2,
                                              float* __restrict__ out) {
    const int n = blockIdx.x * 4 + (threadIdx.x >> 6);
    if (n >= N_NODES) return;
    const int lane = threadIdx.x & 63;
    const float adn = a_dst[n];
    const int beg = offs[n], end = offs[n + 1];

    float e0 = a_src[n] + adn;
    e0 = e0 > 0.f ? e0 : NEG_SLOPE * e0;
    float m = e0;
    for (int j = beg; j < end; j++) {
        const int s = srcsort[j];
        float e = a_src[s] + adn;
        e = e > 0.f ? e : NEG_SLOPE * e;
        m = fmaxf(m, e);
    }
    const float w0 = __expf(e0 - m);
    float denom = w0;
    float acc = (lane < NCLS) ? w0 * h2[(size_t)n * NCLS + lane] : 0.f;
    for (int j = beg; j < end; j++) {
        const int s = srcsort[j];
        float e = a_src[s] + adn;
        e = e > 0.f ? e : NEG_SLOPE * e;
        const float wj = __expf(e - m);
        denom += wj;
        if (lane < NCLS) acc = fmaf(wj, h2[(size_t)s * NCLS + lane], acc);
    }
    float o = (lane < NCLS) ? (acc / denom + b2[lane]) : -INFINITY;
    float mx = o;
#pragma unroll
    for (int off = 32; off; off >>= 1) mx = fmaxf(mx, __shfl_xor(mx, off, 64));
    const float ex = (lane < NCLS) ? __expf(o - mx) : 0.f;
    float sm = ex;
#pragma unroll
    for (int off = 32; off; off >>= 1) sm += __shfl_xor(sm, off, 64);
    if (lane < NCLS) out[(size_t)n * NCLS + lane] = ex / sm;
}

// ---------------- launcher ----------------
extern "C" void kernel_launch(void* const* d_in, const int* in_sizes, int n_in,
                              void* d_out, int out_size, void* d_ws, size_t ws_size,
                              hipStream_t stream) {
    const float* x   = (const float*)d_in[0];
    const int*   ei  = (const int*)d_in[1];
    const float* W1v = (const float*)d_in[2];
    const float* as1 = (const float*)d_in[3];
    const float* ad1 = (const float*)d_in[4];
    const float* b1  = (const float*)d_in[5];
    const float* W2v = (const float*)d_in[6];
    const float* as2 = (const float*)d_in[7];
    const float* ad2 = (const float*)d_in[8];
    const float* b2  = (const float*)d_in[9];
    const int E = in_sizes[1] / 2;
    const int* esrc = ei;
    const int* edst = ei + E;

    char* wp = (char*)d_ws;
    auto alloc = [&](size_t bytes) {
        char* p = wp;
        wp += (bytes + 255) & ~(size_t)255;
        return p;
    };
    float* h1     = (float*)alloc((size_t)N_NODES * HC1 * 4);
    float* h1e    = (float*)alloc((size_t)N_NODES * HC1 * 4);
    float* a_src1 = (float*)alloc((size_t)N_NODES * H1H * 4);
    float* a_dst1 = (float*)alloc((size_t)N_NODES * H1H * 4);
    float* a_src2 = (float*)alloc((size_t)N_NODES * 4);
    float* a_dst2 = (float*)alloc((size_t)N_NODES * 4);
    int*   deg    = (int*)alloc((size_t)N_NODES * 4);
    int*   offs   = (int*)alloc((size_t)(N_NODES + 1) * 4);
    int*   cursor = (int*)alloc((size_t)N_NODES * 4);
    int*   bsum   = (int*)alloc(512 * 4);
    int*   boff   = (int*)alloc(512 * 4);
    int*   srcsort= (int*)alloc((size_t)E * 4);
    float* h2     = h1;  // h1 dead after k_agg1; reuse for h2

    hipMemsetAsync(deg, 0, (size_t)N_NODES * 4, stream);

    k_gemm1<<<(N_NODES + TM - 1) / TM, 256, 0, stream>>>(x, W1v, h1);
    k_att1<<<(N_NODES * H1H + 255) / 256, 256, 0, stream>>>(h1, as1, ad1, a_src1, a_dst1);
    k_hist<<<(E + 255) / 256, 256, 0, stream>>>(edst, E, deg);
    const int NB = (N_NODES + 255) / 256;
    k_scan1<<<NB, 256, 0, stream>>>(deg, offs, bsum);
    k_scan2<<<1, 512, 0, stream>>>(bsum, boff, NB);
    k_scan3<<<NB, 256, 0, stream>>>(offs, boff, cursor, E);
    k_scatter<<<(E + 255) / 256, 256, 0, stream>>>(esrc, edst, E, cursor, srcsort);
    k_agg1<<<(N_NODES + 3) / 4, 256, 0, stream>>>(h1, a_src1, a_dst1, offs, srcsort, b1, h1e);
    k_gemm2<<<(N_NODES + 3) / 4, 256, 0, stream>>>(h1e, W2v, as2, ad2, h2, a_src2, a_dst2);
    k_agg2<<<(N_NODES + 3) / 4, 256, 0, stream>>>(h2, a_src2, a_dst2, offs, srcsort, b2, (float*)d_out);
}

// Round 3
// 819.533 us; speedup vs baseline: 1.8695x; 1.4188x over previous
//
#include <hip/hip_runtime.h>
#include <math.h>

#define N_NODES 100000
#define FIN     512
#define H1H     8
#define C1C     8
#define HC1     64
#define NCLS    40
#define NEG_SLOPE 0.2f

// ---------------- Layer-1 GEMM: h1[N,64] = x[N,512] @ W1[512,64] ----------------
#define TM 128
#define TN 64
#define BK 32
#define XS_LD 132

__global__ __launch_bounds__(256) void k_gemm1(const float* __restrict__ x,
                                               const float* __restrict__ W1,
                                               float* __restrict__ h1) {
    __shared__ float xs[BK][XS_LD];
    __shared__ float ws[BK][TN];
    const int tx = threadIdx.x;
    const int row_base = blockIdx.x * TM;

    const int cg = (tx & 15) << 2;
    const int rg = (tx >> 4) << 3;

    float acc[8][4];
#pragma unroll
    for (int i = 0; i < 8; i++)
#pragma unroll
        for (int j = 0; j < 4; j++) acc[i][j] = 0.f;

    for (int k0 = 0; k0 < FIN; k0 += BK) {
#pragma unroll
        for (int i = 0; i < 4; i++) {
            const int f  = tx + 256 * i;
            const int r  = f >> 3;
            const int kq = (f & 7) << 2;
            const int gr = row_base + r;
            float4 v = make_float4(0.f, 0.f, 0.f, 0.f);
            if (gr < N_NODES) v = *(const float4*)(x + (size_t)gr * FIN + k0 + kq);
            xs[kq + 0][r] = v.x;
            xs[kq + 1][r] = v.y;
            xs[kq + 2][r] = v.z;
            xs[kq + 3][r] = v.w;
        }
#pragma unroll
        for (int i = 0; i < 2; i++) {
            const int f  = tx + 256 * i;
            const int kk = f >> 4;
            const int c4 = (f & 15) << 2;
            *(float4*)&ws[kk][c4] = *(const float4*)(W1 + (size_t)(k0 + kk) * TN + c4);
        }
        __syncthreads();
#pragma unroll
        for (int k = 0; k < BK; k++) {
            const float4 xa = *(const float4*)&xs[k][rg];
            const float4 xb = *(const float4*)&xs[k][rg + 4];
            const float4 wv = *(const float4*)&ws[k][cg];
            const float xr[8] = {xa.x, xa.y, xa.z, xa.w, xb.x, xb.y, xb.z, xb.w};
#pragma unroll
            for (int i = 0; i < 8; i++) {
                acc[i][0] = fmaf(xr[i], wv.x, acc[i][0]);
                acc[i][1] = fmaf(xr[i], wv.y, acc[i][1]);
                acc[i][2] = fmaf(xr[i], wv.z, acc[i][2]);
                acc[i][3] = fmaf(xr[i], wv.w, acc[i][3]);
            }
        }
        __syncthreads();
    }
#pragma unroll
    for (int i = 0; i < 8; i++) {
        const int gr = row_base + rg + i;
        if (gr < N_NODES)
            *(float4*)(h1 + (size_t)gr * HC1 + cg) =
                make_float4(acc[i][0], acc[i][1], acc[i][2], acc[i][3]);
    }
}

// ---------------- Layer-1 attention dots ----------------
__global__ __launch_bounds__(256) void k_att1(const float* __restrict__ h1,
                                              const float* __restrict__ att_src,
                                              const float* __restrict__ att_dst,
                                              float* __restrict__ a_src,
                                              float* __restrict__ a_dst) {
    const int tid = blockIdx.x * 256 + threadIdx.x;
    if (tid >= N_NODES * H1H) return;
    const int n = tid >> 3, hh = tid & 7;
    const float* hp = h1 + (size_t)n * HC1 + hh * C1C;
    float s = 0.f, d = 0.f;
#pragma unroll
    for (int c = 0; c < C1C; c++) {
        const float v = hp[c];
        s = fmaf(v, att_src[hh * C1C + c], s);
        d = fmaf(v, att_dst[hh * C1C + c], d);
    }
    a_src[tid] = s;
    a_dst[tid] = d;
}

// ---------------- CSR build ----------------
__global__ void k_hist(const int* __restrict__ dst, int E, int* __restrict__ deg) {
    const int e = blockIdx.x * 256 + threadIdx.x;
    if (e < E) atomicAdd(&deg[dst[e]], 1);
}

__global__ __launch_bounds__(256) void k_scan1(const int* __restrict__ deg,
                                               int* __restrict__ offs,
                                               int* __restrict__ bsum) {
    __shared__ int sm[256];
    const int i = blockIdx.x * 256 + threadIdx.x;
    const int v = (i < N_NODES) ? deg[i] : 0;
    sm[threadIdx.x] = v;
    __syncthreads();
    for (int off = 1; off < 256; off <<= 1) {
        const int t = (threadIdx.x >= off) ? sm[threadIdx.x - off] : 0;
        __syncthreads();
        sm[threadIdx.x] += t;
        __syncthreads();
    }
    if (i < N_NODES) offs[i] = sm[threadIdx.x] - v;
    if (threadIdx.x == 255) bsum[blockIdx.x] = sm[255];
}

__global__ __launch_bounds__(512) void k_scan2(const int* __restrict__ bsum,
                                               int* __restrict__ boff, int nb) {
    __shared__ int sm[512];
    const int v = (threadIdx.x < nb) ? bsum[threadIdx.x] : 0;
    sm[threadIdx.x] = v;
    __syncthreads();
    for (int off = 1; off < 512; off <<= 1) {
        const int t = (threadIdx.x >= off) ? sm[threadIdx.x - off] : 0;
        __syncthreads();
        sm[threadIdx.x] += t;
        __syncthreads();
    }
    if (threadIdx.x < nb) boff[threadIdx.x] = sm[threadIdx.x] - v;
}

__global__ __launch_bounds__(256) void k_scan3(int* __restrict__ offs,
                                               const int* __restrict__ boff,
                                               int* __restrict__ cursor, int E) {
    const int i = blockIdx.x * 256 + threadIdx.x;
    if (i < N_NODES) {
        const int o = offs[i] + boff[blockIdx.x];
        offs[i] = o;
        cursor[i] = o;
    }
    if (i == 0) offs[N_NODES] = E;
}

__global__ void k_scatter(const int* __restrict__ src, const int* __restrict__ dst,
                          int E, int* __restrict__ cursor, int* __restrict__ srcsort) {
    const int e = blockIdx.x * 256 + threadIdx.x;
    if (e < E) {
        const int pos = atomicAdd(&cursor[dst[e]], 1);
        srcsort[pos] = src[e];
    }
}

// ---------------- Layer-1: single-pass batched online softmax + aggregate ----------------
// One wave per dst node; lane = output channel (head = lane>>3). 4-edge batches
// give 4x memory-level parallelism; branchless online-softmax rescale.
__global__ __launch_bounds__(256) void k_agg1(const float* __restrict__ h1,
                                              const float* __restrict__ a_src,
                                              const float* __restrict__ a_dst,
                                              const int* __restrict__ offs,
                                              const int* __restrict__ srcsort,
                                              const float* __restrict__ b1,
                                              float* __restrict__ h1e) {
    const int n = blockIdx.x * 4 + (threadIdx.x >> 6);
    if (n >= N_NODES) return;
    const int lane = threadIdx.x & 63;
    const int hh   = lane >> 3;
    const float adn = a_dst[n * H1H + hh];
    const int beg = offs[n], end = offs[n + 1];

    // self loop seeds the online state: m = e_self, w_self = 1
    float e0 = a_src[n * H1H + hh] + adn;
    e0 = e0 > 0.f ? e0 : NEG_SLOPE * e0;
    float m = e0;
    float denom = 1.f;
    float acc = h1[(size_t)n * HC1 + lane];

    int j = beg;
    for (; j + 4 <= end; j += 4) {
        const int s0 = srcsort[j], s1 = srcsort[j + 1];
        const int s2 = srcsort[j + 2], s3 = srcsort[j + 3];
        const float q0 = a_src[s0 * H1H + hh], q1 = a_src[s1 * H1H + hh];
        const float q2 = a_src[s2 * H1H + hh], q3 = a_src[s3 * H1H + hh];
        const float g0 = h1[(size_t)s0 * HC1 + lane];
        const float g1 = h1[(size_t)s1 * HC1 + lane];
        const float g2 = h1[(size_t)s2 * HC1 + lane];
        const float g3 = h1[(size_t)s3 * HC1 + lane];
        float f0 = q0 + adn; f0 = f0 > 0.f ? f0 : NEG_SLOPE * f0;
        float f1 = q1 + adn; f1 = f1 > 0.f ? f1 : NEG_SLOPE * f1;
        float f2 = q2 + adn; f2 = f2 > 0.f ? f2 : NEG_SLOPE * f2;
        float f3 = q3 + adn; f3 = f3 > 0.f ? f3 : NEG_SLOPE * f3;
        const float nm = fmaxf(m, fmaxf(fmaxf(f0, f1), fmaxf(f2, f3)));
        const float sc = __expf(m - nm);
        const float w0 = __expf(f0 - nm), w1 = __expf(f1 - nm);
        const float w2 = __expf(f2 - nm), w3 = __expf(f3 - nm);
        denom = fmaf(denom, sc, (w0 + w1) + (w2 + w3));
        acc = fmaf(acc, sc, fmaf(w0, g0, fmaf(w1, g1, fmaf(w2, g2, w3 * g3))));
        m = nm;
    }
    for (; j < end; j++) {
        const int s = srcsort[j];
        float e = a_src[s * H1H + hh] + adn;
        e = e > 0.f ? e : NEG_SLOPE * e;
        const float g = h1[(size_t)s * HC1 + lane];
        const float nm = fmaxf(m, e);
        const float sc = __expf(m - nm);
        const float w = __expf(e - nm);
        denom = fmaf(denom, sc, w);
        acc = fmaf(acc, sc, w * g);
        m = nm;
    }
    float v = acc / denom + b1[lane];
    h1e[(size_t)n * HC1 + lane] = v > 0.f ? v : (__expf(v) - 1.f);
}

// ---------------- Layer-2 GEMM (64->40) + attention dots ----------------
__global__ __launch_bounds__(256) void k_gemm2(const float* __restrict__ h1e,
                                               const float* __restrict__ W2,
                                               const float* __restrict__ att_src2,
                                               const float* __restrict__ att_dst2,
                                               float* __restrict__ h2,
                                               float* __restrict__ a_src2,
                                               float* __restrict__ a_dst2) {
    const int n = blockIdx.x * 4 + (threadIdx.x >> 6);
    if (n >= N_NODES) return;
    const int lane = threadIdx.x & 63;
    const float xv = h1e[(size_t)n * HC1 + lane];
    float acc = 0.f;
#pragma unroll
    for (int k = 0; k < HC1; k++) {
        const float xk = __shfl(xv, k, 64);
        const float wv = (lane < NCLS) ? W2[k * NCLS + lane] : 0.f;
        acc = fmaf(xk, wv, acc);
    }
    if (lane < NCLS) h2[(size_t)n * NCLS + lane] = acc;
    float ps = (lane < NCLS) ? acc * att_src2[lane] : 0.f;
    float pd = (lane < NCLS) ? acc * att_dst2[lane] : 0.f;
#pragma unroll
    for (int off = 32; off; off >>= 1) {
        ps += __shfl_xor(ps, off, 64);
        pd += __shfl_xor(pd, off, 64);
    }
    if (lane == 0) {
        a_src2[n] = ps;
        a_dst2[n] = pd;
    }
}

// ---------------- Layer-2: single-pass online softmax-aggregate + class softmax ----------------
__global__ __launch_bounds__(256) void k_agg2(const float* __restrict__ h2,
                                              const float* __restrict__ a_src,
                                              const float* __restrict__ a_dst,
                                              const int* __restrict__ offs,
                                              const int* __restrict__ srcsort,
                                              const float* __restrict__ b2,
                                              float* __restrict__ out) {
    const int n = blockIdx.x * 4 + (threadIdx.x >> 6);
    if (n >= N_NODES) return;
    const int lane = threadIdx.x & 63;
    const float adn = a_dst[n];
    const int beg = offs[n], end = offs[n + 1];

    float e0 = a_src[n] + adn;
    e0 = e0 > 0.f ? e0 : NEG_SLOPE * e0;
    float m = e0;
    float denom = 1.f;
    float acc = (lane < NCLS) ? h2[(size_t)n * NCLS + lane] : 0.f;

    int j = beg;
    for (; j + 4 <= end; j += 4) {
        const int s0 = srcsort[j], s1 = srcsort[j + 1];
        const int s2 = srcsort[j + 2], s3 = srcsort[j + 3];
        const float q0 = a_src[s0], q1 = a_src[s1];
        const float q2 = a_src[s2], q3 = a_src[s3];
        float g0 = 0.f, g1 = 0.f, g2 = 0.f, g3 = 0.f;
        if (lane < NCLS) {
            g0 = h2[(size_t)s0 * NCLS + lane];
            g1 = h2[(size_t)s1 * NCLS + lane];
            g2 = h2[(size_t)s2 * NCLS + lane];
            g3 = h2[(size_t)s3 * NCLS + lane];
        }
        float f0 = q0 + adn; f0 = f0 > 0.f ? f0 : NEG_SLOPE * f0;
        float f1 = q1 + adn; f1 = f1 > 0.f ? f1 : NEG_SLOPE * f1;
        float f2 = q2 + adn; f2 = f2 > 0.f ? f2 : NEG_SLOPE * f2;
        float f3 = q3 + adn; f3 = f3 > 0.f ? f3 : NEG_SLOPE * f3;
        const float nm = fmaxf(m, fmaxf(fmaxf(f0, f1), fmaxf(f2, f3)));
        const float sc = __expf(m - nm);
        const float w0 = __expf(f0 - nm), w1 = __expf(f1 - nm);
        const float w2 = __expf(f2 - nm), w3 = __expf(f3 - nm);
        denom = fmaf(denom, sc, (w0 + w1) + (w2 + w3));
        acc = fmaf(acc, sc, fmaf(w0, g0, fmaf(w1, g1, fmaf(w2, g2, w3 * g3))));
        m = nm;
    }
    for (; j < end; j++) {
        const int s = srcsort[j];
        float e = a_src[s] + adn;
        e = e > 0.f ? e : NEG_SLOPE * e;
        const float g = (lane < NCLS) ? h2[(size_t)s * NCLS + lane] : 0.f;
        const float nm = fmaxf(m, e);
        const float sc = __expf(m - nm);
        const float w = __expf(e - nm);
        denom = fmaf(denom, sc, w);
        acc = fmaf(acc, sc, w * g);
        m = nm;
    }
    float o = (lane < NCLS) ? (acc / denom + b2[lane]) : -INFINITY;
    float mx = o;
#pragma unroll
    for (int off = 32; off; off >>= 1) mx = fmaxf(mx, __shfl_xor(mx, off, 64));
    const float ex = (lane < NCLS) ? __expf(o - mx) : 0.f;
    float sm = ex;
#pragma unroll
    for (int off = 32; off; off >>= 1) sm += __shfl_xor(sm, off, 64);
    if (lane < NCLS) out[(size_t)n * NCLS + lane] = ex / sm;
}

// ---------------- launcher ----------------
extern "C" void kernel_launch(void* const* d_in, const int* in_sizes, int n_in,
                              void* d_out, int out_size, void* d_ws, size_t ws_size,
                              hipStream_t stream) {
    const float* x   = (const float*)d_in[0];
    const int*   ei  = (const int*)d_in[1];
    const float* W1v = (const float*)d_in[2];
    const float* as1 = (const float*)d_in[3];
    const float* ad1 = (const float*)d_in[4];
    const float* b1  = (const float*)d_in[5];
    const float* W2v = (const float*)d_in[6];
    const float* as2 = (const float*)d_in[7];
    const float* ad2 = (const float*)d_in[8];
    const float* b2  = (const float*)d_in[9];
    const int E = in_sizes[1] / 2;
    const int* esrc = ei;
    const int* edst = ei + E;

    char* wp = (char*)d_ws;
    auto alloc = [&](size_t bytes) {
        char* p = wp;
        wp += (bytes + 255) & ~(size_t)255;
        return p;
    };
    float* h1     = (float*)alloc((size_t)N_NODES * HC1 * 4);
    float* h1e    = (float*)alloc((size_t)N_NODES * HC1 * 4);
    float* a_src1 = (float*)alloc((size_t)N_NODES * H1H * 4);
    float* a_dst1 = (float*)alloc((size_t)N_NODES * H1H * 4);
    float* a_src2 = (float*)alloc((size_t)N_NODES * 4);
    float* a_dst2 = (float*)alloc((size_t)N_NODES * 4);
    int*   deg    = (int*)alloc((size_t)N_NODES * 4);
    int*   offs   = (int*)alloc((size_t)(N_NODES + 1) * 4);
    int*   cursor = (int*)alloc((size_t)N_NODES * 4);
    int*   bsum   = (int*)alloc(512 * 4);
    int*   boff   = (int*)alloc(512 * 4);
    int*   srcsort= (int*)alloc((size_t)E * 4);
    float* h2     = h1;  // h1 dead after k_agg1; reuse for h2

    hipMemsetAsync(deg, 0, (size_t)N_NODES * 4, stream);

    k_gemm1<<<(N_NODES + TM - 1) / TM, 256, 0, stream>>>(x, W1v, h1);
    k_att1<<<(N_NODES * H1H + 255) / 256, 256, 0, stream>>>(h1, as1, ad1, a_src1, a_dst1);
    k_hist<<<(E + 255) / 256, 256, 0, stream>>>(edst, E, deg);
    const int NB = (N_NODES + 255) / 256;
    k_scan1<<<NB, 256, 0, stream>>>(deg, offs, bsum);
    k_scan2<<<1, 512, 0, stream>>>(bsum, boff, NB);
    k_scan3<<<NB, 256, 0, stream>>>(offs, boff, cursor, E);
    k_scatter<<<(E + 255) / 256, 256, 0, stream>>>(esrc, edst, E, cursor, srcsort);
    k_agg1<<<(N_NODES + 3) / 4, 256, 0, stream>>>(h1, a_src1, a_dst1, offs, srcsort, b1, h1e);
    k_gemm2<<<(N_NODES + 3) / 4, 256, 0, stream>>>(h1e, W2v, as2, ad2, h2, a_src2, a_dst2);
    k_agg2<<<(N_NODES + 3) / 4, 256, 0, stream>>>(h2, a_src2, a_dst2, offs, srcsort, b2, (float*)d_out);
}

// Round 4
// 718.427 us; speedup vs baseline: 2.1326x; 1.1407x over previous
//
#include <hip/hip_runtime.h>
#include <math.h>

#define N_NODES 100000
#define FIN     512
#define H1H     8
#define C1C     8
#define HC1     64
#define NCLS    40
#define NEG_SLOPE 0.2f

// CSR bucketing: 256 dst-nodes per bucket
#define NPB   256
#define NBUK  391          // ceil(100000/256)
#define EPB   4096         // edges per block in bucket count/fill

// ---------------- Layer-1 GEMM: h1[N,64] = x[N,512] @ W1[512,64] ----------------
// LDS-tiled 128x64, BK=32, register-prefetch pipeline: tile k+1's global loads
// are issued before computing tile k (latency hidden under 2048 cyc of FMA).
#define TM 128
#define TN 64
#define BK 32
#define XS_LD 132

__global__ __launch_bounds__(256) void k_gemm1(const float* __restrict__ x,
                                               const float* __restrict__ W1,
                                               float* __restrict__ h1) {
    __shared__ float xs[BK][XS_LD];
    __shared__ float ws[BK][TN];
    const int tx = threadIdx.x;
    const int row_base = blockIdx.x * TM;
    const int cg = (tx & 15) << 2;
    const int rg = (tx >> 4) << 3;

    float4 xr4[4];
    float4 wr4[2];

    auto load_regs = [&](int k0) {
#pragma unroll
        for (int i = 0; i < 4; i++) {
            const int f  = tx + 256 * i;
            const int r  = f >> 3;
            const int kq = (f & 7) << 2;
            const int gr = row_base + r;
            xr4[i] = (gr < N_NODES) ? *(const float4*)(x + (size_t)gr * FIN + k0 + kq)
                                    : make_float4(0.f, 0.f, 0.f, 0.f);
        }
#pragma unroll
        for (int i = 0; i < 2; i++) {
            const int f  = tx + 256 * i;
            const int kk = f >> 4;
            const int c4 = (f & 15) << 2;
            wr4[i] = *(const float4*)(W1 + (size_t)(k0 + kk) * TN + c4);
        }
    };
    auto store_lds = [&]() {
#pragma unroll
        for (int i = 0; i < 4; i++) {
            const int f  = tx + 256 * i;
            const int r  = f >> 3;
            const int kq = (f & 7) << 2;
            xs[kq + 0][r] = xr4[i].x;
            xs[kq + 1][r] = xr4[i].y;
            xs[kq + 2][r] = xr4[i].z;
            xs[kq + 3][r] = xr4[i].w;
        }
#pragma unroll
        for (int i = 0; i < 2; i++) {
            const int f  = tx + 256 * i;
            const int kk = f >> 4;
            const int c4 = (f & 15) << 2;
            *(float4*)&ws[kk][c4] = wr4[i];
        }
    };

    float acc[8][4];
#pragma unroll
    for (int i = 0; i < 8; i++)
#pragma unroll
        for (int j = 0; j < 4; j++) acc[i][j] = 0.f;

    load_regs(0);
    store_lds();
    __syncthreads();

    for (int k0 = 0; k0 < FIN; k0 += BK) {
        const bool more = (k0 + BK < FIN);
        if (more) load_regs(k0 + BK);   // issued now, waited at store_lds below
#pragma unroll
        for (int k = 0; k < BK; k++) {
            const float4 xa = *(const float4*)&xs[k][rg];
            const float4 xb = *(const float4*)&xs[k][rg + 4];
            const float4 wv = *(const float4*)&ws[k][cg];
            const float xr[8] = {xa.x, xa.y, xa.z, xa.w, xb.x, xb.y, xb.z, xb.w};
#pragma unroll
            for (int i = 0; i < 8; i++) {
                acc[i][0] = fmaf(xr[i], wv.x, acc[i][0]);
                acc[i][1] = fmaf(xr[i], wv.y, acc[i][1]);
                acc[i][2] = fmaf(xr[i], wv.z, acc[i][2]);
                acc[i][3] = fmaf(xr[i], wv.w, acc[i][3]);
            }
        }
        __syncthreads();
        if (more) {
            store_lds();
            __syncthreads();
        }
    }
#pragma unroll
    for (int i = 0; i < 8; i++) {
        const int gr = row_base + rg + i;
        if (gr < N_NODES)
            *(float4*)(h1 + (size_t)gr * HC1 + cg) =
                make_float4(acc[i][0], acc[i][1], acc[i][2], acc[i][3]);
    }
}

// ---------------- Layer-1 attention dots ----------------
__global__ __launch_bounds__(256) void k_att1(const float* __restrict__ h1,
                                              const float* __restrict__ att_src,
                                              const float* __restrict__ att_dst,
                                              float* __restrict__ a_src,
                                              float* __restrict__ a_dst) {
    const int tid = blockIdx.x * 256 + threadIdx.x;
    if (tid >= N_NODES * H1H) return;
    const int n = tid >> 3, hh = tid & 7;
    const float* hp = h1 + (size_t)n * HC1 + hh * C1C;
    float s = 0.f, d = 0.f;
#pragma unroll
    for (int c = 0; c < C1C; c++) {
        const float v = hp[c];
        s = fmaf(v, att_src[hh * C1C + c], s);
        d = fmaf(v, att_dst[hh * C1C + c], d);
    }
    a_src[tid] = s;
    a_dst[tid] = d;
}

// ---------------- CSR build, bucketed (no global fp/int atomics on hot paths) ----
// Pass A1: per-bucket edge counts via block-local LDS histogram.
__global__ __launch_bounds__(256) void k_bcnt(const int* __restrict__ dst, int E,
                                              int* __restrict__ gcnt) {
    __shared__ int lcnt[NBUK];
    for (int i = threadIdx.x; i < NBUK; i += 256) lcnt[i] = 0;
    __syncthreads();
    const int e0 = blockIdx.x * EPB;
#pragma unroll
    for (int i = 0; i < EPB / 256; i++) {
        const int e = e0 + i * 256 + threadIdx.x;
        if (e < E) atomicAdd(&lcnt[dst[e] >> 8], 1);
    }
    __syncthreads();
    for (int i = threadIdx.x; i < NBUK; i += 256)
        if (lcnt[i]) atomicAdd(&gcnt[i], lcnt[i]);
}

// Pass A-scan: exclusive scan of bucket counts -> gbase[NBUK+1], gcur copy.
__global__ __launch_bounds__(512) void k_bscan(const int* __restrict__ gcnt,
                                               int* __restrict__ gbase,
                                               int* __restrict__ gcur, int E) {
    __shared__ int sm[512];
    const int t = threadIdx.x;
    const int v = (t < NBUK) ? gcnt[t] : 0;
    sm[t] = v;
    __syncthreads();
    for (int off = 1; off < 512; off <<= 1) {
        const int u = (t >= off) ? sm[t - off] : 0;
        __syncthreads();
        sm[t] += u;
        __syncthreads();
    }
    if (t < NBUK) {
        const int b = sm[t] - v;
        gbase[t] = b;
        gcur[t]  = b;
    }
    if (t == 0) gbase[NBUK] = E;
}

// Pass A2: write (src,dst) pairs into bucket-contiguous regions.
__global__ __launch_bounds__(256) void k_bfill(const int* __restrict__ src,
                                               const int* __restrict__ dst, int E,
                                               int* __restrict__ gcur,
                                               int2* __restrict__ pairs) {
    __shared__ int lcnt[NBUK];
    __shared__ int lbase[NBUK];
    for (int i = threadIdx.x; i < NBUK; i += 256) lcnt[i] = 0;
    __syncthreads();
    const int e0 = blockIdx.x * EPB;
#pragma unroll
    for (int i = 0; i < EPB / 256; i++) {
        const int e = e0 + i * 256 + threadIdx.x;
        if (e < E) atomicAdd(&lcnt[dst[e] >> 8], 1);
    }
    __syncthreads();
    for (int i = threadIdx.x; i < NBUK; i += 256)
        lbase[i] = lcnt[i] ? atomicAdd(&gcur[i], lcnt[i]) : 0;
    __syncthreads();
#pragma unroll
    for (int i = 0; i < EPB / 256; i++) {
        const int e = e0 + i * 256 + threadIdx.x;
        if (e < E) {
            const int d = dst[e];
            const int pos = atomicAdd(&lbase[d >> 8], 1);
            pairs[pos] = make_int2(src[e], d);
        }
    }
}

// Pass B: one block per bucket. LDS degree hist -> scan -> offs (coalesced)
// -> scatter srcsort via LDS cursors (17KB position window, L2-local).
__global__ __launch_bounds__(256) void k_bscatter(const int2* __restrict__ pairs,
                                                  const int* __restrict__ gbase,
                                                  int* __restrict__ offs,
                                                  int* __restrict__ srcsort, int E) {
    __shared__ int ldeg[NPB];
    __shared__ int ltmp[NPB];
    __shared__ int lcur[NPB];
    const int b = blockIdx.x;
    const int tx = threadIdx.x;
    const int node0 = b << 8;
    const int pbeg = gbase[b];
    const int cnt  = gbase[b + 1] - pbeg;

    ldeg[tx] = 0;
    __syncthreads();
    for (int i = tx; i < cnt; i += 256)
        atomicAdd(&ldeg[pairs[pbeg + i].y - node0], 1);
    __syncthreads();
    const int v = ldeg[tx];
    ltmp[tx] = v;
    __syncthreads();
    for (int off = 1; off < 256; off <<= 1) {
        const int u = (tx >= off) ? ltmp[tx - off] : 0;
        __syncthreads();
        ltmp[tx] += u;
        __syncthreads();
    }
    const int mypos = pbeg + ltmp[tx] - v;
    if (node0 + tx < N_NODES) offs[node0 + tx] = mypos;
    lcur[tx] = mypos;
    if (b == NBUK - 1 && tx == 0) offs[N_NODES] = E;
    __syncthreads();
    for (int i = tx; i < cnt; i += 256) {
        const int2 p = pairs[pbeg + i];
        const int pos = atomicAdd(&lcur[p.y - node0], 1);
        srcsort[pos] = p.x;
    }
}

// ---------------- Layer-1: single-pass batched online softmax + aggregate ----------------
__global__ __launch_bounds__(256) void k_agg1(const float* __restrict__ h1,
                                              const float* __restrict__ a_src,
                                              const float* __restrict__ a_dst,
                                              const int* __restrict__ offs,
                                              const int* __restrict__ srcsort,
                                              const float* __restrict__ b1,
                                              float* __restrict__ h1e) {
    const int n = blockIdx.x * 4 + (threadIdx.x >> 6);
    if (n >= N_NODES) return;
    const int lane = threadIdx.x & 63;
    const int hh   = lane >> 3;
    const float adn = a_dst[n * H1H + hh];
    const int beg = offs[n], end = offs[n + 1];

    float e0 = a_src[n * H1H + hh] + adn;
    e0 = e0 > 0.f ? e0 : NEG_SLOPE * e0;
    float m = e0;
    float denom = 1.f;
    float acc = h1[(size_t)n * HC1 + lane];

    int j = beg;
    for (; j + 4 <= end; j += 4) {
        const int s0 = srcsort[j], s1 = srcsort[j + 1];
        const int s2 = srcsort[j + 2], s3 = srcsort[j + 3];
        const float q0 = a_src[s0 * H1H + hh], q1 = a_src[s1 * H1H + hh];
        const float q2 = a_src[s2 * H1H + hh], q3 = a_src[s3 * H1H + hh];
        const float g0 = h1[(size_t)s0 * HC1 + lane];
        const float g1 = h1[(size_t)s1 * HC1 + lane];
        const float g2 = h1[(size_t)s2 * HC1 + lane];
        const float g3 = h1[(size_t)s3 * HC1 + lane];
        float f0 = q0 + adn; f0 = f0 > 0.f ? f0 : NEG_SLOPE * f0;
        float f1 = q1 + adn; f1 = f1 > 0.f ? f1 : NEG_SLOPE * f1;
        float f2 = q2 + adn; f2 = f2 > 0.f ? f2 : NEG_SLOPE * f2;
        float f3 = q3 + adn; f3 = f3 > 0.f ? f3 : NEG_SLOPE * f3;
        const float nm = fmaxf(m, fmaxf(fmaxf(f0, f1), fmaxf(f2, f3)));
        const float sc = __expf(m - nm);
        const float w0 = __expf(f0 - nm), w1 = __expf(f1 - nm);
        const float w2 = __expf(f2 - nm), w3 = __expf(f3 - nm);
        denom = fmaf(denom, sc, (w0 + w1) + (w2 + w3));
        acc = fmaf(acc, sc, fmaf(w0, g0, fmaf(w1, g1, fmaf(w2, g2, w3 * g3))));
        m = nm;
    }
    for (; j < end; j++) {
        const int s = srcsort[j];
        float e = a_src[s * H1H + hh] + adn;
        e = e > 0.f ? e : NEG_SLOPE * e;
        const float g = h1[(size_t)s * HC1 + lane];
        const float nm = fmaxf(m, e);
        const float sc = __expf(m - nm);
        const float w = __expf(e - nm);
        denom = fmaf(denom, sc, w);
        acc = fmaf(acc, sc, w * g);
        m = nm;
    }
    float v = acc / denom + b1[lane];
    h1e[(size_t)n * HC1 + lane] = v > 0.f ? v : (__expf(v) - 1.f);
}

// ---------------- Layer-2 GEMM (64->40) + attention dots ----------------
__global__ __launch_bounds__(256) void k_gemm2(const float* __restrict__ h1e,
                                               const float* __restrict__ W2,
                                               const float* __restrict__ att_src2,
                                               const float* __restrict__ att_dst2,
                                               float* __restrict__ h2,
                                               float* __restrict__ a_src2,
                                               float* __restrict__ a_dst2) {
    const int n = blockIdx.x * 4 + (threadIdx.x >> 6);
    if (n >= N_NODES) return;
    const int lane = threadIdx.x & 63;
    const float xv = h1e[(size_t)n * HC1 + lane];
    float acc = 0.f;
#pragma unroll
    for (int k = 0; k < HC1; k++) {
        const float xk = __shfl(xv, k, 64);
        const float wv = (lane < NCLS) ? W2[k * NCLS + lane] : 0.f;
        acc = fmaf(xk, wv, acc);
    }
    if (lane < NCLS) h2[(size_t)n * NCLS + lane] = acc;
    float ps = (lane < NCLS) ? acc * att_src2[lane] : 0.f;
    float pd = (lane < NCLS) ? acc * att_dst2[lane] : 0.f;
#pragma unroll
    for (int off = 32; off; off >>= 1) {
        ps += __shfl_xor(ps, off, 64);
        pd += __shfl_xor(pd, off, 64);
    }
    if (lane == 0) {
        a_src2[n] = ps;
        a_dst2[n] = pd;
    }
}

// ---------------- Layer-2: single-pass online softmax-aggregate + class softmax ----------------
__global__ __launch_bounds__(256) void k_agg2(const float* __restrict__ h2,
                                              const float* __restrict__ a_src,
                                              const float* __restrict__ a_dst,
                                              const int* __restrict__ offs,
                                              const int* __restrict__ srcsort,
                                              const float* __restrict__ b2,
                                              float* __restrict__ out) {
    const int n = blockIdx.x * 4 + (threadIdx.x >> 6);
    if (n >= N_NODES) return;
    const int lane = threadIdx.x & 63;
    const float adn = a_dst[n];
    const int beg = offs[n], end = offs[n + 1];

    float e0 = a_src[n] + adn;
    e0 = e0 > 0.f ? e0 : NEG_SLOPE * e0;
    float m = e0;
    float denom = 1.f;
    float acc = (lane < NCLS) ? h2[(size_t)n * NCLS + lane] : 0.f;

    int j = beg;
    for (; j + 4 <= end; j += 4) {
        const int s0 = srcsort[j], s1 = srcsort[j + 1];
        const int s2 = srcsort[j + 2], s3 = srcsort[j + 3];
        const float q0 = a_src[s0], q1 = a_src[s1];
        const float q2 = a_src[s2], q3 = a_src[s3];
        float g0 = 0.f, g1 = 0.f, g2 = 0.f, g3 = 0.f;
        if (lane < NCLS) {
            g0 = h2[(size_t)s0 * NCLS + lane];
            g1 = h2[(size_t)s1 * NCLS + lane];
            g2 = h2[(size_t)s2 * NCLS + lane];
            g3 = h2[(size_t)s3 * NCLS + lane];
        }
        float f0 = q0 + adn; f0 = f0 > 0.f ? f0 : NEG_SLOPE * f0;
        float f1 = q1 + adn; f1 = f1 > 0.f ? f1 : NEG_SLOPE * f1;
        float f2 = q2 + adn; f2 = f2 > 0.f ? f2 : NEG_SLOPE * f2;
        float f3 = q3 + adn; f3 = f3 > 0.f ? f3 : NEG_SLOPE * f3;
        const float nm = fmaxf(m, fmaxf(fmaxf(f0, f1), fmaxf(f2, f3)));
        const float sc = __expf(m - nm);
        const float w0 = __expf(f0 - nm), w1 = __expf(f1 - nm);
        const float w2 = __expf(f2 - nm), w3 = __expf(f3 - nm);
        denom = fmaf(denom, sc, (w0 + w1) + (w2 + w3));
        acc = fmaf(acc, sc, fmaf(w0, g0, fmaf(w1, g1, fmaf(w2, g2, w3 * g3))));
        m = nm;
    }
    for (; j < end; j++) {
        const int s = srcsort[j];
        float e = a_src[s] + adn;
        e = e > 0.f ? e : NEG_SLOPE * e;
        const float g = (lane < NCLS) ? h2[(size_t)s * NCLS + lane] : 0.f;
        const float nm = fmaxf(m, e);
        const float sc = __expf(m - nm);
        const float w = __expf(e - nm);
        denom = fmaf(denom, sc, w);
        acc = fmaf(acc, sc, w * g);
        m = nm;
    }
    float o = (lane < NCLS) ? (acc / denom + b2[lane]) : -INFINITY;
    float mx = o;
#pragma unroll
    for (int off = 32; off; off >>= 1) mx = fmaxf(mx, __shfl_xor(mx, off, 64));
    const float ex = (lane < NCLS) ? __expf(o - mx) : 0.f;
    float sm = ex;
#pragma unroll
    for (int off = 32; off; off >>= 1) sm += __shfl_xor(sm, off, 64);
    if (lane < NCLS) out[(size_t)n * NCLS + lane] = ex / sm;
}

// ---------------- launcher ----------------
extern "C" void kernel_launch(void* const* d_in, const int* in_sizes, int n_in,
                              void* d_out, int out_size, void* d_ws, size_t ws_size,
                              hipStream_t stream) {
    const float* x   = (const float*)d_in[0];
    const int*   ei  = (const int*)d_in[1];
    const float* W1v = (const float*)d_in[2];
    const float* as1 = (const float*)d_in[3];
    const float* ad1 = (const float*)d_in[4];
    const float* b1  = (const float*)d_in[5];
    const float* W2v = (const float*)d_in[6];
    const float* as2 = (const float*)d_in[7];
    const float* ad2 = (const float*)d_in[8];
    const float* b2  = (const float*)d_in[9];
    const int E = in_sizes[1] / 2;
    const int* esrc = ei;
    const int* edst = ei + E;

    char* wp = (char*)d_ws;
    auto alloc = [&](size_t bytes) {
        char* p = wp;
        wp += (bytes + 255) & ~(size_t)255;
        return p;
    };
    float* h1     = (float*)alloc((size_t)N_NODES * HC1 * 4);
    float* h1e    = (float*)alloc((size_t)N_NODES * HC1 * 4);
    float* a_src1 = (float*)alloc((size_t)N_NODES * H1H * 4);
    float* a_dst1 = (float*)alloc((size_t)N_NODES * H1H * 4);
    float* a_src2 = (float*)alloc((size_t)N_NODES * 4);
    float* a_dst2 = (float*)alloc((size_t)N_NODES * 4);
    int*   offs   = (int*)alloc((size_t)(N_NODES + 1) * 4);
    int*   gcnt   = (int*)alloc((size_t)NBUK * 4);
    int*   gbase  = (int*)alloc((size_t)(NBUK + 1) * 4);
    int*   gcur   = (int*)alloc((size_t)NBUK * 4);
    int*   srcsort= (int*)alloc((size_t)E * 4);
    int2*  pairs  = (int2*)alloc((size_t)E * 8);
    float* h2     = h1;  // h1 dead after k_agg1; reuse for h2

    hipMemsetAsync(gcnt, 0, (size_t)NBUK * 4, stream);

    const int NEB = (E + EPB - 1) / EPB;
    k_gemm1<<<(N_NODES + TM - 1) / TM, 256, 0, stream>>>(x, W1v, h1);
    k_att1<<<(N_NODES * H1H + 255) / 256, 256, 0, stream>>>(h1, as1, ad1, a_src1, a_dst1);
    k_bcnt<<<NEB, 256, 0, stream>>>(edst, E, gcnt);
    k_bscan<<<1, 512, 0, stream>>>(gcnt, gbase, gcur, E);
    k_bfill<<<NEB, 256, 0, stream>>>(esrc, edst, E, gcur, pairs);
    k_bscatter<<<NBUK, 256, 0, stream>>>(pairs, gbase, offs, srcsort, E);
    k_agg1<<<(N_NODES + 3) / 4, 256, 0, stream>>>(h1, a_src1, a_dst1, offs, srcsort, b1, h1e);
    k_gemm2<<<(N_NODES + 3) / 4, 256, 0, stream>>>(h1e, W2v, as2, ad2, h2, a_src2, a_dst2);
    k_agg2<<<(N_NODES + 3) / 4, 256, 0, stream>>>(h2, a_src2, a_dst2, offs, srcsort, b2, (float*)d_out);
}

// Round 5
// 696.290 us; speedup vs baseline: 2.2004x; 1.0318x over previous
//
#include <hip/hip_runtime.h>
#include <math.h>

#define N_NODES 100000
#define FIN     512
#define H1H     8
#define C1C     8
#define HC1     64
#define NCLS    40
#define NEG_SLOPE 0.2f

// CSR bucketing: 256 dst-nodes per bucket
#define NPB   256
#define NBUK  391          // ceil(100000/256)
#define EPB   4096         // edges per block in bucket count/fill

// ---------------- Layer-1 GEMM: h1[N,64] = x[N,512] @ W1[512,64] ----------------
// LDS double-buffered, BK=16, ONE barrier per K-iteration. Prefetch regs are
// only 3 float4 (VGPR stays ~60); LDS 2x(16x132+16x64)x4 = 25 KB -> 6 blocks/CU.
#define TM 128
#define TN 64
#define BK 16
#define XS_LD 132

__global__ __launch_bounds__(256) void k_gemm1(const float* __restrict__ x,
                                               const float* __restrict__ W1,
                                               float* __restrict__ h1) {
    __shared__ float xs[2][BK][XS_LD];
    __shared__ float ws[2][BK][TN];
    const int tx = threadIdx.x;
    const int row_base = blockIdx.x * TM;
    const int cg = (tx & 15) << 2;
    const int rg = (tx >> 4) << 3;

    float4 xr4[2];
    float4 wr4;

    auto load_regs = [&](int k0) {
#pragma unroll
        for (int i = 0; i < 2; i++) {
            const int f  = tx + 256 * i;     // 512 float4 = 128 rows x 4
            const int r  = f >> 2;
            const int kq = (f & 3) << 2;
            const int gr = row_base + r;
            xr4[i] = (gr < N_NODES) ? *(const float4*)(x + (size_t)gr * FIN + k0 + kq)
                                    : make_float4(0.f, 0.f, 0.f, 0.f);
        }
        {
            const int kk = tx >> 4;          // 256 float4 = 16 rows x 16
            const int c4 = (tx & 15) << 2;
            wr4 = *(const float4*)(W1 + (size_t)(k0 + kk) * TN + c4);
        }
    };
    auto store_lds = [&](int buf) {
#pragma unroll
        for (int i = 0; i < 2; i++) {
            const int f  = tx + 256 * i;
            const int r  = f >> 2;
            const int kq = (f & 3) << 2;
            xs[buf][kq + 0][r] = xr4[i].x;
            xs[buf][kq + 1][r] = xr4[i].y;
            xs[buf][kq + 2][r] = xr4[i].z;
            xs[buf][kq + 3][r] = xr4[i].w;
        }
        {
            const int kk = tx >> 4;
            const int c4 = (tx & 15) << 2;
            *(float4*)&ws[buf][kk][c4] = wr4;
        }
    };

    float acc[8][4];
#pragma unroll
    for (int i = 0; i < 8; i++)
#pragma unroll
        for (int j = 0; j < 4; j++) acc[i][j] = 0.f;

    load_regs(0);
    store_lds(0);
    __syncthreads();

    int buf = 0;
    for (int k0 = 0; k0 < FIN; k0 += BK, buf ^= 1) {
        const bool more = (k0 + BK < FIN);
        if (more) load_regs(k0 + BK);      // global loads in flight during compute
#pragma unroll
        for (int k = 0; k < BK; k++) {
            const float4 xa = *(const float4*)&xs[buf][k][rg];
            const float4 xb = *(const float4*)&xs[buf][k][rg + 4];
            const float4 wv = *(const float4*)&ws[buf][k][cg];
            const float xr[8] = {xa.x, xa.y, xa.z, xa.w, xb.x, xb.y, xb.z, xb.w};
#pragma unroll
            for (int i = 0; i < 8; i++) {
                acc[i][0] = fmaf(xr[i], wv.x, acc[i][0]);
                acc[i][1] = fmaf(xr[i], wv.y, acc[i][1]);
                acc[i][2] = fmaf(xr[i], wv.z, acc[i][2]);
                acc[i][3] = fmaf(xr[i], wv.w, acc[i][3]);
            }
        }
        if (more) {
            store_lds(buf ^ 1);            // vmcnt satisfied by now; other buffer
            __syncthreads();               // single barrier per iteration
        }
    }
#pragma unroll
    for (int i = 0; i < 8; i++) {
        const int gr = row_base + rg + i;
        if (gr < N_NODES)
            *(float4*)(h1 + (size_t)gr * HC1 + cg) =
                make_float4(acc[i][0], acc[i][1], acc[i][2], acc[i][3]);
    }
}

// ---------------- Layer-1 attention dots ----------------
__global__ __launch_bounds__(256) void k_att1(const float* __restrict__ h1,
                                              const float* __restrict__ att_src,
                                              const float* __restrict__ att_dst,
                                              float* __restrict__ a_src,
                                              float* __restrict__ a_dst) {
    const int tid = blockIdx.x * 256 + threadIdx.x;
    if (tid >= N_NODES * H1H) return;
    const int n = tid >> 3, hh = tid & 7;
    const float* hp = h1 + (size_t)n * HC1 + hh * C1C;
    float s = 0.f, d = 0.f;
#pragma unroll
    for (int c = 0; c < C1C; c++) {
        const float v = hp[c];
        s = fmaf(v, att_src[hh * C1C + c], s);
        d = fmaf(v, att_dst[hh * C1C + c], d);
    }
    a_src[tid] = s;
    a_dst[tid] = d;
}

// ---------------- CSR build, bucketed ----------------
__global__ __launch_bounds__(256) void k_bcnt(const int* __restrict__ dst, int E,
                                              int* __restrict__ gcnt) {
    __shared__ int lcnt[NBUK];
    for (int i = threadIdx.x; i < NBUK; i += 256) lcnt[i] = 0;
    __syncthreads();
    const int e0 = blockIdx.x * EPB;
#pragma unroll
    for (int i = 0; i < EPB / 256; i++) {
        const int e = e0 + i * 256 + threadIdx.x;
        if (e < E) atomicAdd(&lcnt[dst[e] >> 8], 1);
    }
    __syncthreads();
    for (int i = threadIdx.x; i < NBUK; i += 256)
        if (lcnt[i]) atomicAdd(&gcnt[i], lcnt[i]);
}

__global__ __launch_bounds__(512) void k_bscan(const int* __restrict__ gcnt,
                                               int* __restrict__ gbase,
                                               int* __restrict__ gcur, int E) {
    __shared__ int sm[512];
    const int t = threadIdx.x;
    const int v = (t < NBUK) ? gcnt[t] : 0;
    sm[t] = v;
    __syncthreads();
    for (int off = 1; off < 512; off <<= 1) {
        const int u = (t >= off) ? sm[t - off] : 0;
        __syncthreads();
        sm[t] += u;
        __syncthreads();
    }
    if (t < NBUK) {
        const int b = sm[t] - v;
        gbase[t] = b;
        gcur[t]  = b;
    }
    if (t == 0) gbase[NBUK] = E;
}

__global__ __launch_bounds__(256) void k_bfill(const int* __restrict__ src,
                                               const int* __restrict__ dst, int E,
                                               int* __restrict__ gcur,
                                               int2* __restrict__ pairs) {
    __shared__ int lcnt[NBUK];
    __shared__ int lbase[NBUK];
    for (int i = threadIdx.x; i < NBUK; i += 256) lcnt[i] = 0;
    __syncthreads();
    const int e0 = blockIdx.x * EPB;
#pragma unroll
    for (int i = 0; i < EPB / 256; i++) {
        const int e = e0 + i * 256 + threadIdx.x;
        if (e < E) atomicAdd(&lcnt[dst[e] >> 8], 1);
    }
    __syncthreads();
    for (int i = threadIdx.x; i < NBUK; i += 256)
        lbase[i] = lcnt[i] ? atomicAdd(&gcur[i], lcnt[i]) : 0;
    __syncthreads();
#pragma unroll
    for (int i = 0; i < EPB / 256; i++) {
        const int e = e0 + i * 256 + threadIdx.x;
        if (e < E) {
            const int d = dst[e];
            const int pos = atomicAdd(&lbase[d >> 8], 1);
            pairs[pos] = make_int2(src[e], d);
        }
    }
}

__global__ __launch_bounds__(256) void k_bscatter(const int2* __restrict__ pairs,
                                                  const int* __restrict__ gbase,
                                                  int* __restrict__ offs,
                                                  int* __restrict__ srcsort, int E) {
    __shared__ int ldeg[NPB];
    __shared__ int ltmp[NPB];
    __shared__ int lcur[NPB];
    const int b = blockIdx.x;
    const int tx = threadIdx.x;
    const int node0 = b << 8;
    const int pbeg = gbase[b];
    const int cnt  = gbase[b + 1] - pbeg;

    ldeg[tx] = 0;
    __syncthreads();
    for (int i = tx; i < cnt; i += 256)
        atomicAdd(&ldeg[pairs[pbeg + i].y - node0], 1);
    __syncthreads();
    const int v = ldeg[tx];
    ltmp[tx] = v;
    __syncthreads();
    for (int off = 1; off < 256; off <<= 1) {
        const int u = (tx >= off) ? ltmp[tx - off] : 0;
        __syncthreads();
        ltmp[tx] += u;
        __syncthreads();
    }
    const int mypos = pbeg + ltmp[tx] - v;
    if (node0 + tx < N_NODES) offs[node0 + tx] = mypos;
    lcur[tx] = mypos;
    if (b == NBUK - 1 && tx == 0) offs[N_NODES] = E;
    __syncthreads();
    for (int i = tx; i < cnt; i += 256) {
        const int2 p = pairs[pbeg + i];
        const int pos = atomicAdd(&lcur[p.y - node0], 1);
        srcsort[pos] = p.x;
    }
}

// ---------------- Layer-1: single-pass batched online softmax + aggregate ----------------
__global__ __launch_bounds__(256) void k_agg1(const float* __restrict__ h1,
                                              const float* __restrict__ a_src,
                                              const float* __restrict__ a_dst,
                                              const int* __restrict__ offs,
                                              const int* __restrict__ srcsort,
                                              const float* __restrict__ b1,
                                              float* __restrict__ h1e) {
    const int n = blockIdx.x * 4 + (threadIdx.x >> 6);
    if (n >= N_NODES) return;
    const int lane = threadIdx.x & 63;
    const int hh   = lane >> 3;
    const float adn = a_dst[n * H1H + hh];
    const int beg = offs[n], end = offs[n + 1];

    float e0 = a_src[n * H1H + hh] + adn;
    e0 = e0 > 0.f ? e0 : NEG_SLOPE * e0;
    float m = e0;
    float denom = 1.f;
    float acc = h1[(size_t)n * HC1 + lane];

    int j = beg;
    for (; j + 4 <= end; j += 4) {
        const int s0 = srcsort[j], s1 = srcsort[j + 1];
        const int s2 = srcsort[j + 2], s3 = srcsort[j + 3];
        const float q0 = a_src[s0 * H1H + hh], q1 = a_src[s1 * H1H + hh];
        const float q2 = a_src[s2 * H1H + hh], q3 = a_src[s3 * H1H + hh];
        const float g0 = h1[(size_t)s0 * HC1 + lane];
        const float g1 = h1[(size_t)s1 * HC1 + lane];
        const float g2 = h1[(size_t)s2 * HC1 + lane];
        const float g3 = h1[(size_t)s3 * HC1 + lane];
        float f0 = q0 + adn; f0 = f0 > 0.f ? f0 : NEG_SLOPE * f0;
        float f1 = q1 + adn; f1 = f1 > 0.f ? f1 : NEG_SLOPE * f1;
        float f2 = q2 + adn; f2 = f2 > 0.f ? f2 : NEG_SLOPE * f2;
        float f3 = q3 + adn; f3 = f3 > 0.f ? f3 : NEG_SLOPE * f3;
        const float nm = fmaxf(m, fmaxf(fmaxf(f0, f1), fmaxf(f2, f3)));
        const float sc = __expf(m - nm);
        const float w0 = __expf(f0 - nm), w1 = __expf(f1 - nm);
        const float w2 = __expf(f2 - nm), w3 = __expf(f3 - nm);
        denom = fmaf(denom, sc, (w0 + w1) + (w2 + w3));
        acc = fmaf(acc, sc, fmaf(w0, g0, fmaf(w1, g1, fmaf(w2, g2, w3 * g3))));
        m = nm;
    }
    for (; j < end; j++) {
        const int s = srcsort[j];
        float e = a_src[s * H1H + hh] + adn;
        e = e > 0.f ? e : NEG_SLOPE * e;
        const float g = h1[(size_t)s * HC1 + lane];
        const float nm = fmaxf(m, e);
        const float sc = __expf(m - nm);
        const float w = __expf(e - nm);
        denom = fmaf(denom, sc, w);
        acc = fmaf(acc, sc, w * g);
        m = nm;
    }
    float v = acc / denom + b1[lane];
    h1e[(size_t)n * HC1 + lane] = v > 0.f ? v : (__expf(v) - 1.f);
}

// ---------------- Layer-2 GEMM (64->40) + attention dots ----------------
__global__ __launch_bounds__(256) void k_gemm2(const float* __restrict__ h1e,
                                               const float* __restrict__ W2,
                                               const float* __restrict__ att_src2,
                                               const float* __restrict__ att_dst2,
                                               float* __restrict__ h2,
                                               float* __restrict__ a_src2,
                                               float* __restrict__ a_dst2) {
    const int n = blockIdx.x * 4 + (threadIdx.x >> 6);
    if (n >= N_NODES) return;
    const int lane = threadIdx.x & 63;
    const float xv = h1e[(size_t)n * HC1 + lane];
    float acc = 0.f;
#pragma unroll
    for (int k = 0; k < HC1; k++) {
        const float xk = __shfl(xv, k, 64);
        const float wv = (lane < NCLS) ? W2[k * NCLS + lane] : 0.f;
        acc = fmaf(xk, wv, acc);
    }
    if (lane < NCLS) h2[(size_t)n * NCLS + lane] = acc;
    float ps = (lane < NCLS) ? acc * att_src2[lane] : 0.f;
    float pd = (lane < NCLS) ? acc * att_dst2[lane] : 0.f;
#pragma unroll
    for (int off = 32; off; off >>= 1) {
        ps += __shfl_xor(ps, off, 64);
        pd += __shfl_xor(pd, off, 64);
    }
    if (lane == 0) {
        a_src2[n] = ps;
        a_dst2[n] = pd;
    }
}

// ---------------- Layer-2: single-pass online softmax-aggregate + class softmax ----------------
__global__ __launch_bounds__(256) void k_agg2(const float* __restrict__ h2,
                                              const float* __restrict__ a_src,
                                              const float* __restrict__ a_dst,
                                              const int* __restrict__ offs,
                                              const int* __restrict__ srcsort,
                                              const float* __restrict__ b2,
                                              float* __restrict__ out) {
    const int n = blockIdx.x * 4 + (threadIdx.x >> 6);
    if (n >= N_NODES) return;
    const int lane = threadIdx.x & 63;
    const float adn = a_dst[n];
    const int beg = offs[n], end = offs[n + 1];

    float e0 = a_src[n] + adn;
    e0 = e0 > 0.f ? e0 : NEG_SLOPE * e0;
    float m = e0;
    float denom = 1.f;
    float acc = (lane < NCLS) ? h2[(size_t)n * NCLS + lane] : 0.f;

    int j = beg;
    for (; j + 4 <= end; j += 4) {
        const int s0 = srcsort[j], s1 = srcsort[j + 1];
        const int s2 = srcsort[j + 2], s3 = srcsort[j + 3];
        const float q0 = a_src[s0], q1 = a_src[s1];
        const float q2 = a_src[s2], q3 = a_src[s3];
        float g0 = 0.f, g1 = 0.f, g2 = 0.f, g3 = 0.f;
        if (lane < NCLS) {
            g0 = h2[(size_t)s0 * NCLS + lane];
            g1 = h2[(size_t)s1 * NCLS + lane];
            g2 = h2[(size_t)s2 * NCLS + lane];
            g3 = h2[(size_t)s3 * NCLS + lane];
        }
        float f0 = q0 + adn; f0 = f0 > 0.f ? f0 : NEG_SLOPE * f0;
        float f1 = q1 + adn; f1 = f1 > 0.f ? f1 : NEG_SLOPE * f1;
        float f2 = q2 + adn; f2 = f2 > 0.f ? f2 : NEG_SLOPE * f2;
        float f3 = q3 + adn; f3 = f3 > 0.f ? f3 : NEG_SLOPE * f3;
        const float nm = fmaxf(m, fmaxf(fmaxf(f0, f1), fmaxf(f2, f3)));
        const float sc = __expf(m - nm);
        const float w0 = __expf(f0 - nm), w1 = __expf(f1 - nm);
        const float w2 = __expf(f2 - nm), w3 = __expf(f3 - nm);
        denom = fmaf(denom, sc, (w0 + w1) + (w2 + w3));
        acc = fmaf(acc, sc, fmaf(w0, g0, fmaf(w1, g1, fmaf(w2, g2, w3 * g3))));
        m = nm;
    }
    for (; j < end; j++) {
        const int s = srcsort[j];
        float e = a_src[s] + adn;
        e = e > 0.f ? e : NEG_SLOPE * e;
        const float g = (lane < NCLS) ? h2[(size_t)s * NCLS + lane] : 0.f;
        const float nm = fmaxf(m, e);
        const float sc = __expf(m - nm);
        const float w = __expf(e - nm);
        denom = fmaf(denom, sc, w);
        acc = fmaf(acc, sc, w * g);
        m = nm;
    }
    float o = (lane < NCLS) ? (acc / denom + b2[lane]) : -INFINITY;
    float mx = o;
#pragma unroll
    for (int off = 32; off; off >>= 1) mx = fmaxf(mx, __shfl_xor(mx, off, 64));
    const float ex = (lane < NCLS) ? __expf(o - mx) : 0.f;
    float sm = ex;
#pragma unroll
    for (int off = 32; off; off >>= 1) sm += __shfl_xor(sm, off, 64);
    if (lane < NCLS) out[(size_t)n * NCLS + lane] = ex / sm;
}

// ---------------- launcher ----------------
extern "C" void kernel_launch(void* const* d_in, const int* in_sizes, int n_in,
                              void* d_out, int out_size, void* d_ws, size_t ws_size,
                              hipStream_t stream) {
    const float* x   = (const float*)d_in[0];
    const int*   ei  = (const int*)d_in[1];
    const float* W1v = (const float*)d_in[2];
    const float* as1 = (const float*)d_in[3];
    const float* ad1 = (const float*)d_in[4];
    const float* b1  = (const float*)d_in[5];
    const float* W2v = (const float*)d_in[6];
    const float* as2 = (const float*)d_in[7];
    const float* ad2 = (const float*)d_in[8];
    const float* b2  = (const float*)d_in[9];
    const int E = in_sizes[1] / 2;
    const int* esrc = ei;
    const int* edst = ei + E;

    char* wp = (char*)d_ws;
    auto alloc = [&](size_t bytes) {
        char* p = wp;
        wp += (bytes + 255) & ~(size_t)255;
        return p;
    };
    float* h1     = (float*)alloc((size_t)N_NODES * HC1 * 4);
    float* h1e    = (float*)alloc((size_t)N_NODES * HC1 * 4);
    float* a_src1 = (float*)alloc((size_t)N_NODES * H1H * 4);
    float* a_dst1 = (float*)alloc((size_t)N_NODES * H1H * 4);
    float* a_src2 = (float*)alloc((size_t)N_NODES * 4);
    float* a_dst2 = (float*)alloc((size_t)N_NODES * 4);
    int*   offs   = (int*)alloc((size_t)(N_NODES + 1) * 4);
    int*   gcnt   = (int*)alloc((size_t)NBUK * 4);
    int*   gbase  = (int*)alloc((size_t)(NBUK + 1) * 4);
    int*   gcur   = (int*)alloc((size_t)NBUK * 4);
    int*   srcsort= (int*)alloc((size_t)E * 4);
    int2*  pairs  = (int2*)alloc((size_t)E * 8);
    float* h2     = h1;  // h1 dead after k_agg1; reuse for h2

    hipMemsetAsync(gcnt, 0, (size_t)NBUK * 4, stream);

    const int NEB = (E + EPB - 1) / EPB;
    k_gemm1<<<(N_NODES + TM - 1) / TM, 256, 0, stream>>>(x, W1v, h1);
    k_att1<<<(N_NODES * H1H + 255) / 256, 256, 0, stream>>>(h1, as1, ad1, a_src1, a_dst1);
    k_bcnt<<<NEB, 256, 0, stream>>>(edst, E, gcnt);
    k_bscan<<<1, 512, 0, stream>>>(gcnt, gbase, gcur, E);
    k_bfill<<<NEB, 256, 0, stream>>>(esrc, edst, E, gcur, pairs);
    k_bscatter<<<NBUK, 256, 0, stream>>>(pairs, gbase, offs, srcsort, E);
    k_agg1<<<(N_NODES + 3) / 4, 256, 0, stream>>>(h1, a_src1, a_dst1, offs, srcsort, b1, h1e);
    k_gemm2<<<(N_NODES + 3) / 4, 256, 0, stream>>>(h1e, W2v, as2, ad2, h2, a_src2, a_dst2);
    k_agg2<<<(N_NODES + 3) / 4, 256, 0, stream>>>(h2, a_src2, a_dst2, offs, srcsort, b2, (float*)d_out);
}

// Round 6
// 609.372 us; speedup vs baseline: 2.5142x; 1.1426x over previous
//
#include <hip/hip_runtime.h>
#include <math.h>

#define N_NODES 100000
#define FIN     512
#define H1H     8
#define C1C     8
#define HC1     64
#define NCLS    40
#define NEG_SLOPE 0.2f

// CSR bucketing: 256 dst-nodes per bucket
#define NPB   256
#define NBUK  391          // ceil(100000/256)
#define EPB   4096         // edges per block in bucket count/fill

// ---------------- Layer-1 GEMM + fused attention dots ----------------
// LDS double-buffered, BK=16, one barrier per K-iteration (R4 win: VGPR~60,
// 6 blocks/CU). Epilogue computes a_src1/a_dst1 in-register (att1 fused).
#define TM 128
#define TN 64
#define BK 16
#define XS_LD 132

__global__ __launch_bounds__(256) void k_gemm1(const float* __restrict__ x,
                                               const float* __restrict__ W1,
                                               const float* __restrict__ att_src,
                                               const float* __restrict__ att_dst,
                                               float* __restrict__ h1,
                                               float* __restrict__ a_src,
                                               float* __restrict__ a_dst) {
    __shared__ float xs[2][BK][XS_LD];
    __shared__ float ws[2][BK][TN];
    const int tx = threadIdx.x;
    const int row_base = blockIdx.x * TM;
    const int cg = (tx & 15) << 2;
    const int rg = (tx >> 4) << 3;

    float4 xr4[2];
    float4 wr4;

    auto load_regs = [&](int k0) {
#pragma unroll
        for (int i = 0; i < 2; i++) {
            const int f  = tx + 256 * i;     // 512 float4 = 128 rows x 4
            const int r  = f >> 2;
            const int kq = (f & 3) << 2;
            const int gr = row_base + r;
            xr4[i] = (gr < N_NODES) ? *(const float4*)(x + (size_t)gr * FIN + k0 + kq)
                                    : make_float4(0.f, 0.f, 0.f, 0.f);
        }
        {
            const int kk = tx >> 4;          // 256 float4 = 16 rows x 16
            const int c4 = (tx & 15) << 2;
            wr4 = *(const float4*)(W1 + (size_t)(k0 + kk) * TN + c4);
        }
    };
    auto store_lds = [&](int buf) {
#pragma unroll
        for (int i = 0; i < 2; i++) {
            const int f  = tx + 256 * i;
            const int r  = f >> 2;
            const int kq = (f & 3) << 2;
            xs[buf][kq + 0][r] = xr4[i].x;
            xs[buf][kq + 1][r] = xr4[i].y;
            xs[buf][kq + 2][r] = xr4[i].z;
            xs[buf][kq + 3][r] = xr4[i].w;
        }
        {
            const int kk = tx >> 4;
            const int c4 = (tx & 15) << 2;
            *(float4*)&ws[buf][kk][c4] = wr4;
        }
    };

    float acc[8][4];
#pragma unroll
    for (int i = 0; i < 8; i++)
#pragma unroll
        for (int j = 0; j < 4; j++) acc[i][j] = 0.f;

    load_regs(0);
    store_lds(0);
    __syncthreads();

    int buf = 0;
    for (int k0 = 0; k0 < FIN; k0 += BK, buf ^= 1) {
        const bool more = (k0 + BK < FIN);
        if (more) load_regs(k0 + BK);
#pragma unroll
        for (int k = 0; k < BK; k++) {
            const float4 xa = *(const float4*)&xs[buf][k][rg];
            const float4 xb = *(const float4*)&xs[buf][k][rg + 4];
            const float4 wv = *(const float4*)&ws[buf][k][cg];
            const float xr[8] = {xa.x, xa.y, xa.z, xa.w, xb.x, xb.y, xb.z, xb.w};
#pragma unroll
            for (int i = 0; i < 8; i++) {
                acc[i][0] = fmaf(xr[i], wv.x, acc[i][0]);
                acc[i][1] = fmaf(xr[i], wv.y, acc[i][1]);
                acc[i][2] = fmaf(xr[i], wv.z, acc[i][2]);
                acc[i][3] = fmaf(xr[i], wv.w, acc[i][3]);
            }
        }
        if (more) {
            store_lds(buf ^ 1);
            __syncthreads();
        }
    }

    // epilogue: store h1 + fused attention dots (cols cg..cg+3 are half of
    // head cg>>3; partner lane tx^1 holds the other half)
    const float4 asv = *(const float4*)(att_src + cg);
    const float4 adv = *(const float4*)(att_dst + cg);
    const int head = cg >> 3;
#pragma unroll
    for (int i = 0; i < 8; i++) {
        const int gr = row_base + rg + i;
        if (gr < N_NODES)
            *(float4*)(h1 + (size_t)gr * HC1 + cg) =
                make_float4(acc[i][0], acc[i][1], acc[i][2], acc[i][3]);
        float ps = acc[i][0] * asv.x + acc[i][1] * asv.y + acc[i][2] * asv.z + acc[i][3] * asv.w;
        float pd = acc[i][0] * adv.x + acc[i][1] * adv.y + acc[i][2] * adv.z + acc[i][3] * adv.w;
        ps += __shfl_xor(ps, 1, 64);
        pd += __shfl_xor(pd, 1, 64);
        if (!(tx & 1) && gr < N_NODES) {
            a_src[gr * H1H + head] = ps;
            a_dst[gr * H1H + head] = pd;
        }
    }
}

// ---------------- CSR build, bucketed ----------------
__global__ __launch_bounds__(256) void k_bcnt(const int* __restrict__ dst, int E,
                                              int* __restrict__ gcnt) {
    __shared__ int lcnt[NBUK];
    for (int i = threadIdx.x; i < NBUK; i += 256) lcnt[i] = 0;
    __syncthreads();
    const int e0 = blockIdx.x * EPB;
#pragma unroll
    for (int i = 0; i < EPB / 256; i++) {
        const int e = e0 + i * 256 + threadIdx.x;
        if (e < E) atomicAdd(&lcnt[dst[e] >> 8], 1);
    }
    __syncthreads();
    for (int i = threadIdx.x; i < NBUK; i += 256)
        if (lcnt[i]) atomicAdd(&gcnt[i], lcnt[i]);
}

__global__ __launch_bounds__(512) void k_bscan(const int* __restrict__ gcnt,
                                               int* __restrict__ gbase,
                                               int* __restrict__ gcur, int E) {
    __shared__ int sm[512];
    const int t = threadIdx.x;
    const int v = (t < NBUK) ? gcnt[t] : 0;
    sm[t] = v;
    __syncthreads();
    for (int off = 1; off < 512; off <<= 1) {
        const int u = (t >= off) ? sm[t - off] : 0;
        __syncthreads();
        sm[t] += u;
        __syncthreads();
    }
    if (t < NBUK) {
        const int b = sm[t] - v;
        gbase[t] = b;
        gcur[t]  = b;
    }
    if (t == 0) gbase[NBUK] = E;
}

__global__ __launch_bounds__(256) void k_bfill(const int* __restrict__ src,
                                               const int* __restrict__ dst, int E,
                                               int* __restrict__ gcur,
                                               int2* __restrict__ pairs) {
    __shared__ int lcnt[NBUK];
    __shared__ int lbase[NBUK];
    for (int i = threadIdx.x; i < NBUK; i += 256) lcnt[i] = 0;
    __syncthreads();
    const int e0 = blockIdx.x * EPB;
#pragma unroll
    for (int i = 0; i < EPB / 256; i++) {
        const int e = e0 + i * 256 + threadIdx.x;
        if (e < E) atomicAdd(&lcnt[dst[e] >> 8], 1);
    }
    __syncthreads();
    for (int i = threadIdx.x; i < NBUK; i += 256)
        lbase[i] = lcnt[i] ? atomicAdd(&gcur[i], lcnt[i]) : 0;
    __syncthreads();
#pragma unroll
    for (int i = 0; i < EPB / 256; i++) {
        const int e = e0 + i * 256 + threadIdx.x;
        if (e < E) {
            const int d = dst[e];
            const int pos = atomicAdd(&lbase[d >> 8], 1);
            pairs[pos] = make_int2(src[e], d);
        }
    }
}

__global__ __launch_bounds__(256) void k_bscatter(const int2* __restrict__ pairs,
                                                  const int* __restrict__ gbase,
                                                  int* __restrict__ offs,
                                                  int* __restrict__ srcsort, int E) {
    __shared__ int ldeg[NPB];
    __shared__ int ltmp[NPB];
    __shared__ int lcur[NPB];
    const int b = blockIdx.x;
    const int tx = threadIdx.x;
    const int node0 = b << 8;
    const int pbeg = gbase[b];
    const int cnt  = gbase[b + 1] - pbeg;

    ldeg[tx] = 0;
    __syncthreads();
    for (int i = tx; i < cnt; i += 256)
        atomicAdd(&ldeg[pairs[pbeg + i].y - node0], 1);
    __syncthreads();
    const int v = ldeg[tx];
    ltmp[tx] = v;
    __syncthreads();
    for (int off = 1; off < 256; off <<= 1) {
        const int u = (tx >= off) ? ltmp[tx - off] : 0;
        __syncthreads();
        ltmp[tx] += u;
        __syncthreads();
    }
    const int mypos = pbeg + ltmp[tx] - v;
    if (node0 + tx < N_NODES) offs[node0 + tx] = mypos;
    lcur[tx] = mypos;
    if (b == NBUK - 1 && tx == 0) offs[N_NODES] = E;
    __syncthreads();
    for (int i = tx; i < cnt; i += 256) {
        const int2 p = pairs[pbeg + i];
        const int pos = atomicAdd(&lcur[p.y - node0], 1);
        srcsort[pos] = p.x;
    }
}

// ---------------- Layer-1: single-pass batched online softmax + aggregate ----------------
__global__ __launch_bounds__(256) void k_agg1(const float* __restrict__ h1,
                                              const float* __restrict__ a_src,
                                              const float* __restrict__ a_dst,
                                              const int* __restrict__ offs,
                                              const int* __restrict__ srcsort,
                                              const float* __restrict__ b1,
                                              float* __restrict__ h1e) {
    const int n = blockIdx.x * 4 + (threadIdx.x >> 6);
    if (n >= N_NODES) return;
    const int lane = threadIdx.x & 63;
    const int hh   = lane >> 3;
    const float adn = a_dst[n * H1H + hh];
    const int beg = offs[n], end = offs[n + 1];

    float e0 = a_src[n * H1H + hh] + adn;
    e0 = e0 > 0.f ? e0 : NEG_SLOPE * e0;
    float m = e0;
    float denom = 1.f;
    float acc = h1[(size_t)n * HC1 + lane];

    int j = beg;
    for (; j + 4 <= end; j += 4) {
        const int s0 = srcsort[j], s1 = srcsort[j + 1];
        const int s2 = srcsort[j + 2], s3 = srcsort[j + 3];
        const float q0 = a_src[s0 * H1H + hh], q1 = a_src[s1 * H1H + hh];
        const float q2 = a_src[s2 * H1H + hh], q3 = a_src[s3 * H1H + hh];
        const float g0 = h1[(size_t)s0 * HC1 + lane];
        const float g1 = h1[(size_t)s1 * HC1 + lane];
        const float g2 = h1[(size_t)s2 * HC1 + lane];
        const float g3 = h1[(size_t)s3 * HC1 + lane];
        float f0 = q0 + adn; f0 = f0 > 0.f ? f0 : NEG_SLOPE * f0;
        float f1 = q1 + adn; f1 = f1 > 0.f ? f1 : NEG_SLOPE * f1;
        float f2 = q2 + adn; f2 = f2 > 0.f ? f2 : NEG_SLOPE * f2;
        float f3 = q3 + adn; f3 = f3 > 0.f ? f3 : NEG_SLOPE * f3;
        const float nm = fmaxf(m, fmaxf(fmaxf(f0, f1), fmaxf(f2, f3)));
        const float sc = __expf(m - nm);
        const float w0 = __expf(f0 - nm), w1 = __expf(f1 - nm);
        const float w2 = __expf(f2 - nm), w3 = __expf(f3 - nm);
        denom = fmaf(denom, sc, (w0 + w1) + (w2 + w3));
        acc = fmaf(acc, sc, fmaf(w0, g0, fmaf(w1, g1, fmaf(w2, g2, w3 * g3))));
        m = nm;
    }
    for (; j < end; j++) {
        const int s = srcsort[j];
        float e = a_src[s * H1H + hh] + adn;
        e = e > 0.f ? e : NEG_SLOPE * e;
        const float g = h1[(size_t)s * HC1 + lane];
        const float nm = fmaxf(m, e);
        const float sc = __expf(m - nm);
        const float w = __expf(e - nm);
        denom = fmaf(denom, sc, w);
        acc = fmaf(acc, sc, w * g);
        m = nm;
    }
    float v = acc / denom + b1[lane];
    h1e[(size_t)n * HC1 + lane] = v > 0.f ? v : (__expf(v) - 1.f);
}

// ---------------- Layer-2 GEMM (64->40), LDS-tiled, + fused attention dots ----
// 128 nodes/block; thread = 4 nodes x 5 classes (20 acc). Per 4-k step:
// 9 ds_read_b128 vs 80 fma. hs[ng][k][4nodes] pad 65 -> conflict-free reads.
#define TM2 128
__global__ __launch_bounds__(256) void k_gemm2(const float* __restrict__ h1e,
                                               const float* __restrict__ W2,
                                               const float* __restrict__ att_src2,
                                               const float* __restrict__ att_dst2,
                                               float* __restrict__ h2,
                                               float* __restrict__ a_src2,
                                               float* __restrict__ a_dst2) {
    __shared__ float hs[32][65][4];   // [node_group][k(+pad)][node_in_group]
    __shared__ float w2t[NCLS][68];   // transposed W2, padded
    __shared__ float asv[NCLS], adv[NCLS];
    const int tx = threadIdx.x;
    const int node0 = blockIdx.x * TM2;

    for (int f = tx; f < HC1 * NCLS; f += 256) {
        const int k = f / NCLS, c = f - k * NCLS;
        w2t[c][k] = W2[f];
    }
    if (tx < NCLS) {
        asv[tx] = att_src2[tx];
        adv[tx] = att_dst2[tx];
    }
#pragma unroll
    for (int i = 0; i < 8; i++) {
        const int f  = tx + 256 * i;      // 2048 float4 = 128 rows x 16
        const int n  = f >> 4;
        const int k4 = (f & 15) << 2;
        const int gn = node0 + n;
        const float4 v = (gn < N_NODES) ? *(const float4*)(h1e + (size_t)gn * HC1 + k4)
                                        : make_float4(0.f, 0.f, 0.f, 0.f);
        const int ng = n >> 2, ni = n & 3;
        hs[ng][k4 + 0][ni] = v.x;
        hs[ng][k4 + 1][ni] = v.y;
        hs[ng][k4 + 2][ni] = v.z;
        hs[ng][k4 + 3][ni] = v.w;
    }
    __syncthreads();

    const int ng = tx >> 3;          // 0..31 -> nodes ng*4..ng*4+3
    const int cg = tx & 7;           // 0..7  -> classes cg*5..cg*5+4
    const int c0 = cg * 5;

    float acc[4][5];
#pragma unroll
    for (int i = 0; i < 4; i++)
#pragma unroll
        for (int j = 0; j < 5; j++) acc[i][j] = 0.f;

    for (int k = 0; k < HC1; k += 4) {
        float4 hv[4];
#pragma unroll
        for (int t = 0; t < 4; t++) hv[t] = *(const float4*)&hs[ng][k + t][0];
#pragma unroll
        for (int j = 0; j < 5; j++) {
            const float4 wv = *(const float4*)&w2t[c0 + j][k];
            acc[0][j] = fmaf(hv[0].x, wv.x, fmaf(hv[1].x, wv.y, fmaf(hv[2].x, wv.z, fmaf(hv[3].x, wv.w, acc[0][j]))));
            acc[1][j] = fmaf(hv[0].y, wv.x, fmaf(hv[1].y, wv.y, fmaf(hv[2].y, wv.z, fmaf(hv[3].y, wv.w, acc[1][j]))));
            acc[2][j] = fmaf(hv[0].z, wv.x, fmaf(hv[1].z, wv.y, fmaf(hv[2].z, wv.z, fmaf(hv[3].z, wv.w, acc[2][j]))));
            acc[3][j] = fmaf(hv[0].w, wv.x, fmaf(hv[1].w, wv.y, fmaf(hv[2].w, wv.z, fmaf(hv[3].w, wv.w, acc[3][j]))));
        }
    }

    // store h2 + fused att dots (reduce partials over the 8 cg lanes)
    float ps[4], pd[4];
#pragma unroll
    for (int i = 0; i < 4; i++) {
        const int gn = node0 + ng * 4 + i;
        float s = 0.f, d = 0.f;
#pragma unroll
        for (int j = 0; j < 5; j++) {
            s = fmaf(acc[i][j], asv[c0 + j], s);
            d = fmaf(acc[i][j], adv[c0 + j], d);
        }
        ps[i] = s;
        pd[i] = d;
        if (gn < N_NODES) {
#pragma unroll
            for (int j = 0; j < 5; j++)
                h2[(size_t)gn * NCLS + c0 + j] = acc[i][j];
        }
    }
#pragma unroll
    for (int off = 1; off < 8; off <<= 1) {
#pragma unroll
        for (int i = 0; i < 4; i++) {
            ps[i] += __shfl_xor(ps[i], off, 64);
            pd[i] += __shfl_xor(pd[i], off, 64);
        }
    }
    if (cg == 0) {
#pragma unroll
        for (int i = 0; i < 4; i++) {
            const int gn = node0 + ng * 4 + i;
            if (gn < N_NODES) {
                a_src2[gn] = ps[i];
                a_dst2[gn] = pd[i];
            }
        }
    }
}

// ---------------- Layer-2: single-pass online softmax-aggregate + class softmax ----------------
__global__ __launch_bounds__(256) void k_agg2(const float* __restrict__ h2,
                                              const float* __restrict__ a_src,
                                              const float* __restrict__ a_dst,
                                              const int* __restrict__ offs,
                                              const int* __restrict__ srcsort,
                                              const float* __restrict__ b2,
                                              float* __restrict__ out) {
    const int n = blockIdx.x * 4 + (threadIdx.x >> 6);
    if (n >= N_NODES) return;
    const int lane = threadIdx.x & 63;
    const float adn = a_dst[n];
    const int beg = offs[n], end = offs[n + 1];

    float e0 = a_src[n] + adn;
    e0 = e0 > 0.f ? e0 : NEG_SLOPE * e0;
    float m = e0;
    float denom = 1.f;
    float acc = (lane < NCLS) ? h2[(size_t)n * NCLS + lane] : 0.f;

    int j = beg;
    for (; j + 4 <= end; j += 4) {
        const int s0 = srcsort[j], s1 = srcsort[j + 1];
        const int s2 = srcsort[j + 2], s3 = srcsort[j + 3];
        const float q0 = a_src[s0], q1 = a_src[s1];
        const float q2 = a_src[s2], q3 = a_src[s3];
        float g0 = 0.f, g1 = 0.f, g2 = 0.f, g3 = 0.f;
        if (lane < NCLS) {
            g0 = h2[(size_t)s0 * NCLS + lane];
            g1 = h2[(size_t)s1 * NCLS + lane];
            g2 = h2[(size_t)s2 * NCLS + lane];
            g3 = h2[(size_t)s3 * NCLS + lane];
        }
        float f0 = q0 + adn; f0 = f0 > 0.f ? f0 : NEG_SLOPE * f0;
        float f1 = q1 + adn; f1 = f1 > 0.f ? f1 : NEG_SLOPE * f1;
        float f2 = q2 + adn; f2 = f2 > 0.f ? f2 : NEG_SLOPE * f2;
        float f3 = q3 + adn; f3 = f3 > 0.f ? f3 : NEG_SLOPE * f3;
        const float nm = fmaxf(m, fmaxf(fmaxf(f0, f1), fmaxf(f2, f3)));
        const float sc = __expf(m - nm);
        const float w0 = __expf(f0 - nm), w1 = __expf(f1 - nm);
        const float w2 = __expf(f2 - nm), w3 = __expf(f3 - nm);
        denom = fmaf(denom, sc, (w0 + w1) + (w2 + w3));
        acc = fmaf(acc, sc, fmaf(w0, g0, fmaf(w1, g1, fmaf(w2, g2, w3 * g3))));
        m = nm;
    }
    for (; j < end; j++) {
        const int s = srcsort[j];
        float e = a_src[s] + adn;
        e = e > 0.f ? e : NEG_SLOPE * e;
        const float g = (lane < NCLS) ? h2[(size_t)s * NCLS + lane] : 0.f;
        const float nm = fmaxf(m, e);
        const float sc = __expf(m - nm);
        const float w = __expf(e - nm);
        denom = fmaf(denom, sc, w);
        acc = fmaf(acc, sc, w * g);
        m = nm;
    }
    float o = (lane < NCLS) ? (acc / denom + b2[lane]) : -INFINITY;
    float mx = o;
#pragma unroll
    for (int off = 32; off; off >>= 1) mx = fmaxf(mx, __shfl_xor(mx, off, 64));
    const float ex = (lane < NCLS) ? __expf(o - mx) : 0.f;
    float sm = ex;
#pragma unroll
    for (int off = 32; off; off >>= 1) sm += __shfl_xor(sm, off, 64);
    if (lane < NCLS) out[(size_t)n * NCLS + lane] = ex / sm;
}

// ---------------- launcher ----------------
extern "C" void kernel_launch(void* const* d_in, const int* in_sizes, int n_in,
                              void* d_out, int out_size, void* d_ws, size_t ws_size,
                              hipStream_t stream) {
    const float* x   = (const float*)d_in[0];
    const int*   ei  = (const int*)d_in[1];
    const float* W1v = (const float*)d_in[2];
    const float* as1 = (const float*)d_in[3];
    const float* ad1 = (const float*)d_in[4];
    const float* b1  = (const float*)d_in[5];
    const float* W2v = (const float*)d_in[6];
    const float* as2 = (const float*)d_in[7];
    const float* ad2 = (const float*)d_in[8];
    const float* b2  = (const float*)d_in[9];
    const int E = in_sizes[1] / 2;
    const int* esrc = ei;
    const int* edst = ei + E;

    char* wp = (char*)d_ws;
    auto alloc = [&](size_t bytes) {
        char* p = wp;
        wp += (bytes + 255) & ~(size_t)255;
        return p;
    };
    float* h1     = (float*)alloc((size_t)N_NODES * HC1 * 4);
    float* h1e    = (float*)alloc((size_t)N_NODES * HC1 * 4);
    float* a_src1 = (float*)alloc((size_t)N_NODES * H1H * 4);
    float* a_dst1 = (float*)alloc((size_t)N_NODES * H1H * 4);
    float* a_src2 = (float*)alloc((size_t)N_NODES * 4);
    float* a_dst2 = (float*)alloc((size_t)N_NODES * 4);
    int*   offs   = (int*)alloc((size_t)(N_NODES + 1) * 4);
    int*   gcnt   = (int*)alloc((size_t)NBUK * 4);
    int*   gbase  = (int*)alloc((size_t)(NBUK + 1) * 4);
    int*   gcur   = (int*)alloc((size_t)NBUK * 4);
    int*   srcsort= (int*)alloc((size_t)E * 4);
    int2*  pairs  = (int2*)alloc((size_t)E * 8);
    float* h2     = h1;  // h1 dead after k_agg1; reuse for h2

    hipMemsetAsync(gcnt, 0, (size_t)NBUK * 4, stream);

    const int NEB = (E + EPB - 1) / EPB;
    k_gemm1<<<(N_NODES + TM - 1) / TM, 256, 0, stream>>>(x, W1v, as1, ad1, h1, a_src1, a_dst1);
    k_bcnt<<<NEB, 256, 0, stream>>>(edst, E, gcnt);
    k_bscan<<<1, 512, 0, stream>>>(gcnt, gbase, gcur, E);
    k_bfill<<<NEB, 256, 0, stream>>>(esrc, edst, E, gcur, pairs);
    k_bscatter<<<NBUK, 256, 0, stream>>>(pairs, gbase, offs, srcsort, E);
    k_agg1<<<(N_NODES + 3) / 4, 256, 0, stream>>>(h1, a_src1, a_dst1, offs, srcsort, b1, h1e);
    k_gemm2<<<(N_NODES + TM2 - 1) / TM2, 256, 0, stream>>>(h1e, W2v, as2, ad2, h2, a_src2, a_dst2);
    k_agg2<<<(N_NODES + 3) / 4, 256, 0, stream>>>(h2, a_src2, a_dst2, offs, srcsort, b2, (float*)d_out);
}